// Round 18
// baseline (763.743 us; speedup 1.0000x reference)
//
#include <hip/hip_runtime.h>
#include <hip/hip_bf16.h>

#define BATCH 8
#define TSEQ 8
#define HH 64
#define WW 64
#define HID 64
#define PT 10   // T + NUM_NODE - 1
#define PIXN 32768   // BATCH*HH*WW

typedef __bf16 bf16_t;
typedef __bf16 bf16x8 __attribute__((ext_vector_type(8)));
typedef float  f32x4  __attribute__((ext_vector_type(4)));

__device__ __forceinline__ float fsigmoid(float v) {
    float e = __builtin_amdgcn_exp2f(-1.4426950408889634f * v);
    return __builtin_amdgcn_rcpf(1.0f + e);
}
__device__ __forceinline__ float ftanh(float v) {
    float e = __builtin_amdgcn_exp2f(2.8853900817779268f * v);   // e^(2v)
    return 1.0f - 2.0f * __builtin_amdgcn_rcpf(1.0f + e);
}

// ---------------------------------------------------------------------------
// Weight pack for 16x16x32 MFMA B-fragments (unchanged):
//   dst[((chunk*NT16 + nt)*64 + lane)*8 + j],  chunk = tap*KC + kc  (KC=CinPad/32)
//     = w[co = nt*16 + (lane&15)][ci = kc*32 + (lane>>4)*8 + j][tap]
// ---------------------------------------------------------------------------
struct PackSeg { const float* src; bf16_t* dst; int NT16; int KC; int CinReal; int begin; };
struct PackArgs { PackSeg s[12]; int total; };

__global__ void wpack_all(PackArgs P) {
    int idx = blockIdx.x * 256 + threadIdx.x;
    if (idx >= P.total) return;
    int si = 0;
#pragma unroll
    for (int i = 1; i < 12; ++i) if (idx >= P.s[i].begin) si = i;
    PackSeg sg = P.s[si];
    int l = idx - sg.begin;
    int j    = l & 7;
    int lane = (l >> 3) & 63;
    int rest = l >> 9;
    int nt   = rest % sg.NT16;
    int chunk = rest / sg.NT16;
    int kc  = chunk % sg.KC;
    int tap = chunk / sg.KC;
    int co = nt * 16 + (lane & 15);
    int ci = kc * 32 + (lane >> 4) * 8 + j;
    float v = (ci < sg.CinReal) ? sg.src[((long)co * sg.CinReal + ci) * 9 + tap] : 0.0f;
    sg.dst[l] = (bf16_t)v;
}

// ---------------------------------------------------------------------------
// Fused proj+int kernel, ROWS=1 (512 blocks -> 2 blocks/CU resident).
// Phase A: stage input 5 rows x 66 px x 64ch (PSBX 136).
// Phase B: proj conv -> p on 3 rows (halo recompute), bf16 into LDS (PSBP 72),
//          borders zeroed (exact zero-pad semantics).
// Phase C: int conv on p -> bu for 1 row; LDS-bounced coalesced store.
// XIN=1: fuses fp32->bf16 x conversion into staging (bit-identical rounding).
// ---------------------------------------------------------------------------
struct PJ {
    const bf16_t* X;
    const float*  Xf;
    int t;
    const bf16_t* Wpj;
    const float*  bpj;
    const bf16_t* Wit;
    const float*  bit;
    bf16_t* outB;
};
struct PJs { PJ u[8]; };

template <int XIN>
__global__ __launch_bounds__(256, 2) void projint_k(PJs P) {
    constexpr int PSBX = 136;
    constexpr int PSBP = 72;
    constexpr int POFF = 5 * 66 * PSBX;           // 44,880
    __shared__ __align__(16) char smem[POFF + 3 * 66 * PSBP];   // 59,136

    const PJ u = P.u[blockIdx.y];
    const int tid = threadIdx.x, lane = tid & 63, w = tid >> 6;
    const int b = blockIdx.x & 7, y0 = blockIdx.x >> 3;     // 1 output row
    const int l15 = lane & 15, kg = lane >> 4;

    const bf16_t* wpp = u.Wpj + (size_t)(w & 1) * 512 + (size_t)lane * 8;
    bf16x8 ring[4];
#pragma unroll
    for (int i = 0; i < 4; ++i) ring[i] = *(const bf16x8*)(wpp + (size_t)i * 1024);

    if (XIN) {
        for (int c = tid; c < 5 * 66; c += 256) {
            int ry = c / 66, px = c - ry * 66;
            int gy = y0 + ry - 2, gx = px - 1;
            bf16x8 v0 = {};
            if ((unsigned)gy < 64u && (unsigned)gx < 64u) {
                long base = ((((long)b * TSEQ + u.t) * 3) * 64 + gy) * 64 + gx;
                v0[0] = (bf16_t)u.Xf[base];
                v0[1] = (bf16_t)u.Xf[base + 4096];
                v0[2] = (bf16_t)u.Xf[base + 8192];
            }
            char* dst = smem + (ry * 66 + px) * PSBX;
            *(bf16x8*)dst = v0;
            bf16x8 zz = {};
#pragma unroll
            for (int c2 = 1; c2 < 8; ++c2) *(bf16x8*)(dst + c2 * 16) = zz;
        }
    } else {
        for (int c = tid; c < 5 * 66 * 8; c += 256) {
            int ry = c / (66 * 8);
            int r  = c - ry * (66 * 8);
            int px = r >> 3, c2 = r & 7;
            int gy = y0 + ry - 2, gx = px - 1;
            bf16x8 v = {};
            if ((unsigned)gy < 64u && (unsigned)gx < 64u)
                v = *(const bf16x8*)(u.X + (((long)b * 64 + gy) * 64 + gx) * 64 + c2 * 8);
            *(bf16x8*)(smem + (ry * 66 + px) * PSBX + c2 * 16) = v;
        }
    }
    // zero p halo cols (3 rows x cols {0,65} x 4 chunks)
    if (tid < 24) {
        int row = tid >> 3;
        int col = ((tid >> 2) & 1) ? 65 : 0;
        int chk = tid & 3;
        *(bf16x8*)(smem + POFF + (row * 66 + col) * PSBP + chk * 16) = (bf16x8){};
    }
    if (y0 == 0)
        for (int i = tid; i < 66 * 4; i += 256)
            *(bf16x8*)(smem + POFF + (0 * 66 + (i >> 2)) * PSBP + (i & 3) * 16) = (bf16x8){};
    if (y0 == 63)
        for (int i = tid; i < 66 * 4; i += 256)
            *(bf16x8*)(smem + POFF + (2 * 66 + (i >> 2)) * PSBP + (i & 3) * 16) = (bf16x8){};
    __syncthreads();

    // ---- phase B: proj conv, 12 m-tiles (3 p-rows x 64 px), 6 per wave ----
    const int ntp = w & 1, mtb = (w >> 1) * 6;
    f32x4 pacc[6];
    {
        float bv = u.bpj[ntp * 16 + l15];
#pragma unroll
        for (int mi = 0; mi < 6; ++mi) pacc[mi] = (f32x4){bv, bv, bv, bv};
    }
#pragma unroll
    for (int ch = 0; ch < 18; ++ch) {
        const int tap = ch >> 1, kc = ch & 1;
        const int ky = tap / 3, kx = tap % 3;
        bf16x8 bcur = ring[ch & 3];
        if (ch + 4 < 18) ring[ch & 3] = *(const bf16x8*)(wpp + (size_t)(ch + 4) * 1024);
#pragma unroll
        for (int mi = 0; mi < 6; ++mi) {
            const int mt = mtb + mi;
            const int prow = mt >> 2, xseg = mt & 3;
            const int addr = ((prow + ky) * 66 + xseg * 16 + l15 + kx) * PSBX
                           + kg * 16 + kc * 64;
            bf16x8 a = *(const bf16x8*)(smem + addr);
            pacc[mi] = __builtin_amdgcn_mfma_f32_16x16x32_bf16(a, bcur, pacc[mi], 0, 0, 0);
        }
    }
    const bf16_t* wpi = u.Wit + (size_t)(w & 1) * 512 + (size_t)lane * 8;
    bf16x8 ring2[4];
#pragma unroll
    for (int i = 0; i < 4; ++i) ring2[i] = *(const bf16x8*)(wpi + (size_t)i * 1024);
    // write p (bf16) into LDS p-region; skip out-of-image rows (left zeroed)
#pragma unroll
    for (int mi = 0; mi < 6; ++mi) {
        const int mt = mtb + mi;
        const int prow = mt >> 2, xseg = mt & 3;
        const int gyp = y0 - 1 + prow;
        if (gyp >= 0 && gyp < 64) {
            const int co = ntp * 16 + l15;
#pragma unroll
            for (int reg = 0; reg < 4; ++reg) {
                const int pxi = xseg * 16 + kg * 4 + reg;
                *(bf16_t*)(smem + POFF + (prow * 66 + pxi + 1) * PSBP + co * 2) =
                    (bf16_t)pacc[mi][reg];
            }
        }
    }
    __syncthreads();

    // ---- phase C: int conv on p, 4 m-tiles (1 row), 2 per wave ----
    const int nti = w & 1, mtb2 = (w >> 1) * 2;
    f32x4 iacc[2];
    {
        float bv = u.bit[nti * 16 + l15];
#pragma unroll
        for (int mi = 0; mi < 2; ++mi) iacc[mi] = (f32x4){bv, bv, bv, bv};
    }
#pragma unroll
    for (int ch = 0; ch < 9; ++ch) {
        const int ky = ch / 3, kx = ch % 3;
        bf16x8 bcur = ring2[ch & 3];
        if (ch + 4 < 9) ring2[ch & 3] = *(const bf16x8*)(wpi + (size_t)(ch + 4) * 1024);
#pragma unroll
        for (int mi = 0; mi < 2; ++mi) {
            const int xseg = mtb2 + mi;
            const int addr = POFF + (ky * 66 + xseg * 16 + l15 + kx) * PSBP + kg * 16;
            bf16x8 a = *(const bf16x8*)(smem + addr);
            iacc[mi] = __builtin_amdgcn_mfma_f32_16x16x32_bf16(a, bcur, iacc[mi], 0, 0, 0);
        }
    }
    // ---- epilogue: bounce bu, coalesced store ----
    bf16_t* so = (bf16_t*)smem;                 // [64][40]
#pragma unroll
    for (int mi = 0; mi < 2; ++mi) {
        const int xseg = mtb2 + mi;
        const int lpx0 = xseg * 16 + kg * 4;
        const int co = nti * 16 + l15;
#pragma unroll
        for (int reg = 0; reg < 4; ++reg)
            so[(lpx0 + reg) * 40 + co] = (bf16_t)iacc[mi][reg];
    }
    __syncthreads();
    const long pixbase = ((long)b * 64 + y0) * 64;
    for (int i = tid; i < 64 * 4; i += 256) {
        const int p = i >> 2, cc = (i & 3) * 8;
        *(bf16x8*)(u.outB + (pixbase + p) * 32 + cc) = *(const bf16x8*)(so + p * 40 + cc);
    }
}

// ---------------------------------------------------------------------------
// Gates / cand conv, ROWS=1 (512 blocks -> up to 4 blocks/CU).
// MODE 1: gates -> rh bf16 + z f32. MODE 2: cand -> h fp32 + h bf16.
// MODE 3: cand final -> NCHW fp32 d_out.
// ---------------------------------------------------------------------------
struct NP {
    const bf16_t* A0;
    const bf16_t* A1;
    const float*  Zf;
    const float*  Hf;
    const bf16_t* Hb;
    const bf16_t* Wp;
    const float*  bias;
    bf16_t* outB;
    float*  outF;
};
struct NPs { NP n[3]; };

template <int CIN0, int CIN1, int COUT, int MODE, int MINW>
__global__ __launch_bounds__(256, MINW) void mconv(NPs P)
{
    constexpr int CIN  = CIN0 + CIN1;
    constexpr int NT16 = COUT / 16;
    constexpr int NCH  = CIN / 8;
    constexpr int KC   = CIN / 32;
    constexpr int NCHUNK = 9 * KC;
    constexpr int PSB  = CIN * 2 + 8;
    constexpr int NT_W = (NT16 > 4) ? NT16 / 4 : 1;   // gates 2, cand 1
    constexpr int NW_N = NT16 / NT_W;                 // 4
    constexpr int MT_W = 4;                           // all waves sweep 4 m-tiles
    constexpr int PF   = 4;
    constexpr int ASMEM = 3 * 66 * PSB;
    constexpr int OSMEM = (MODE == 1 || MODE == 2) ? 64 * 68 * 4 + 64 * 72 * 2
                                                   : 64 * 69 * 4;
    constexpr int SMEM  = (ASMEM > OSMEM) ? ASMEM : OSMEM;

    const NP np   = P.n[blockIdx.y];
    const int tid  = threadIdx.x;
    const int lane = tid & 63;
    const int w    = tid >> 6;
    const int b  = blockIdx.x & 7;
    const int y0 = blockIdx.x >> 3;               // 1 output row

    __shared__ __align__(16) char smem[SMEM];

    const int nt0 = (w % NW_N) * NT_W;
    const int l15 = lane & 15;
    const int kg  = lane >> 4;

    const bf16_t* wp0 = np.Wp + (size_t)nt0 * 512 + (size_t)lane * 8;
    bf16x8 ring[PF][NT_W];
#pragma unroll
    for (int i = 0; i < PF; ++i)
#pragma unroll
        for (int ni = 0; ni < NT_W; ++ni)
            ring[i][ni] = *(const bf16x8*)(wp0 + (size_t)i * (NT16 * 512) + ni * 512);

    for (int c = tid; c < 3 * 66 * NCH; c += 256) {
        int ry = c / (66 * NCH);
        int r  = c - ry * 66 * NCH;
        int px = r / NCH;
        int c2 = r - px * NCH;
        int gy = y0 + ry - 1, gx = px - 1;
        bf16x8 v = {};
        if ((unsigned)gy < 64u && (unsigned)gx < 64u) {
            long pix = ((long)b * 64 + gy) * 64 + gx;
            int ci = c2 * 8;
            if (CIN1 == 0 || ci < CIN0) v = *(const bf16x8*)(np.A0 + pix * CIN0 + ci);
            else                        v = *(const bf16x8*)(np.A1 + pix * CIN1 + (ci - CIN0));
        }
        *(bf16x8*)(smem + (ry * 66 + px) * PSB + c2 * 16) = v;
    }
    __syncthreads();

    int ab[3];
#pragma unroll
    for (int kx = 0; kx < 3; ++kx)
        ab[kx] = (l15 + kx) * PSB + kg * 16;

    f32x4 acc[MT_W][NT_W];
#pragma unroll
    for (int mi = 0; mi < MT_W; ++mi)
#pragma unroll
        for (int ni = 0; ni < NT_W; ++ni) {
            float bv = np.bias[(nt0 + ni) * 16 + l15];
            acc[mi][ni] = (f32x4){bv, bv, bv, bv};
        }

#pragma unroll
    for (int ch = 0; ch < NCHUNK; ++ch) {
        const int tap = ch / KC, kc = ch % KC;
        const int ky = tap / 3, kx = tap % 3;
        bf16x8 bcur[NT_W];
#pragma unroll
        for (int ni = 0; ni < NT_W; ++ni) bcur[ni] = ring[ch % PF][ni];
        if (ch + PF < NCHUNK) {
#pragma unroll
            for (int ni = 0; ni < NT_W; ++ni)
                ring[ch % PF][ni] =
                    *(const bf16x8*)(wp0 + (size_t)(ch + PF) * (NT16 * 512) + ni * 512);
        }
#pragma unroll
        for (int mi = 0; mi < MT_W; ++mi) {
            const int imm = ky * (66 * PSB) + mi * (16 * PSB) + kc * 64;
            bf16x8 a = *(const bf16x8*)(smem + ab[kx] + imm);
#pragma unroll
            for (int ni = 0; ni < NT_W; ++ni)
                acc[mi][ni] = __builtin_amdgcn_mfma_f32_16x16x32_bf16(
                    a, bcur[ni], acc[mi][ni], 0, 0, 0);
        }
    }

    __syncthreads();
    const long pixbase = ((long)b * 64 + y0) * 64;   // 64 contiguous pixels

    if (MODE == 1) {
        bf16_t* srh = (bf16_t*)smem;                         // [64][72] bf16
        float*  sz  = (float*)(smem + 64 * 72 * 2);          // [64][68] f32
#pragma unroll
        for (int mi = 0; mi < MT_W; ++mi) {
            const int lpx0 = mi * 16 + kg * 4;
#pragma unroll
            for (int ni = 0; ni < NT_W; ++ni) {
                const int co = (nt0 + ni) * 16 + l15;
#pragma unroll
                for (int reg = 0; reg < 4; ++reg) {
                    const int lpx = lpx0 + reg;
                    float s = fsigmoid(acc[mi][ni][reg]);
                    if (co < HID) {
                        float hv = (float)np.Hb[(pixbase + lpx) * HID + co];
                        srh[lpx * 72 + co] = (bf16_t)(s * hv);   // rh
                    } else {
                        sz[lpx * 68 + (co - HID)] = s;           // z
                    }
                }
            }
        }
        __syncthreads();
        for (int i = tid; i < 64 * 8; i += 256) {
            const int p = i >> 3, cc = (i & 7) * 8;
            *(bf16x8*)(np.outB + (pixbase + p) * HID + cc) =
                *(const bf16x8*)(srh + p * 72 + cc);
        }
        for (int i = tid; i < 64 * 16; i += 256) {
            const int p = i >> 4, cc = (i & 15) * 4;
            *(f32x4*)(np.outF + (pixbase + p) * HID + cc) =
                *(const f32x4*)(sz + p * 68 + cc);
        }
    } else if (MODE == 2) {
        float*  shf = (float*)smem;                          // [64][68] f32
        bf16_t* shb = (bf16_t*)(smem + 64 * 68 * 4);         // [64][72] bf16
#pragma unroll
        for (int mi = 0; mi < MT_W; ++mi) {
            const int lpx0 = mi * 16 + kg * 4;
#pragma unroll
            for (int ni = 0; ni < NT_W; ++ni) {
                const int co = (nt0 + ni) * 16 + l15;
#pragma unroll
                for (int reg = 0; reg < 4; ++reg) {
                    const int lpx = lpx0 + reg;
                    float cd = ftanh(acc[mi][ni][reg]);
                    float z  = np.Zf[(pixbase + lpx) * HID + co];
                    float ho = np.Hf[(pixbase + lpx) * HID + co];
                    float hn = z * ho + (1.0f - z) * cd;
                    shf[lpx * 68 + co] = hn;
                    shb[lpx * 72 + co] = (bf16_t)hn;
                }
            }
        }
        __syncthreads();
        for (int i = tid; i < 64 * 16; i += 256) {
            const int p = i >> 4, cc = (i & 15) * 4;
            *(f32x4*)(np.outF + (pixbase + p) * HID + cc) =
                *(const f32x4*)(shf + p * 68 + cc);
        }
        for (int i = tid; i < 64 * 8; i += 256) {
            const int p = i >> 3, cc = (i & 7) * 8;
            *(bf16x8*)(np.outB + (pixbase + p) * HID + cc) =
                *(const bf16x8*)(shb + p * 72 + cc);
        }
    } else {   // MODE 3: final cand -> NCHW fp32 output directly
        float* shf = (float*)smem;                           // [64][69] f32
#pragma unroll
        for (int mi = 0; mi < MT_W; ++mi) {
            const int lpx0 = mi * 16 + kg * 4;
#pragma unroll
            for (int ni = 0; ni < NT_W; ++ni) {
                const int co = (nt0 + ni) * 16 + l15;
#pragma unroll
                for (int reg = 0; reg < 4; ++reg) {
                    const int lpx = lpx0 + reg;
                    float cd = ftanh(acc[mi][ni][reg]);
                    float z  = np.Zf[(pixbase + lpx) * HID + co];
                    float ho = np.Hf[(pixbase + lpx) * HID + co];
                    shf[lpx * 69 + co] = z * ho + (1.0f - z) * cd;
                }
            }
        }
        __syncthreads();
        // NCHW: out[((b*64+co)*64 + y0)*64 + x], contiguous in x
        for (int i = tid; i < 64 * 16; i += 256) {
            const int co = i >> 4;
            const int cc = (i & 15) * 4;
            f32x4 v = { shf[(cc + 0) * 69 + co],
                        shf[(cc + 1) * 69 + co],
                        shf[(cc + 2) * 69 + co],
                        shf[(cc + 3) * 69 + co] };
            *(f32x4*)(np.outF + (((long)b * 64 + co) * 64 + y0) * 64 + cc) = v;
        }
    }
}

// ---------------------------------------------------------------------------
extern "C" void kernel_launch(void* const* d_in, const int* in_sizes, int n_in,
                              void* d_out, int out_size, void* d_ws, size_t ws_size,
                              hipStream_t stream) {
    const float* x    = (const float*)d_in[0];
    const float* Win0 = (const float*)d_in[1];
    const float* bin0 = (const float*)d_in[2];
    const float* We10 = (const float*)d_in[3];
    const float* be10 = (const float*)d_in[4];
    const float* We21 = (const float*)d_in[5];
    const float* be21 = (const float*)d_in[6];
    const float* Wint[3] = {(const float*)d_in[7],  (const float*)d_in[13], (const float*)d_in[19]};
    const float* bint[3] = {(const float*)d_in[8],  (const float*)d_in[14], (const float*)d_in[20]};
    const float* Wg[3]   = {(const float*)d_in[9],  (const float*)d_in[15], (const float*)d_in[21]};
    const float* bg[3]   = {(const float*)d_in[10], (const float*)d_in[16], (const float*)d_in[22]};
    const float* Wc[3]   = {(const float*)d_in[11], (const float*)d_in[17], (const float*)d_in[23]};
    const float* bc[3]   = {(const float*)d_in[12], (const float*)d_in[18], (const float*)d_in[24]};
    (void)in_sizes; (void)n_in; (void)out_size; (void)ws_size;

    const long PIX  = (long)PIXN;
    const size_t HFSZ = (size_t)PIX * HID * 4;
    const size_t HBSZ = (size_t)PIX * HID * 2;
    const long PSZ  = PIX * 32;
    const long RHSZ = PIX * HID;
    const long ZSZ  = PIX * HID;

    char* wsb = (char*)d_ws;
    size_t off = 0;
    auto alloc = [&](size_t bytes) -> char* {
        char* q = wsb + off;
        off = (off + bytes + 255) & ~(size_t)255;
        return q;
    };

    // zero-group (contiguous)
    float*  hF[6]; bf16_t* hB[6];
    hF[0] = (float*)alloc(HFSZ); hF[1] = (float*)alloc(HFSZ); hF[2] = (float*)alloc(HFSZ);
    hB[0] = (bf16_t*)alloc(HBSZ); hB[1] = (bf16_t*)alloc(HBSZ); hB[2] = (bf16_t*)alloc(HBSZ);
    const size_t zeroBytes = 3 * HFSZ + 3 * HBSZ;
    hF[3] = (float*)alloc(HFSZ); hF[4] = (float*)alloc(HFSZ); hF[5] = (float*)alloc(HFSZ);
    hB[3] = (bf16_t*)alloc(HBSZ); hB[4] = (bf16_t*)alloc(HBSZ); hB[5] = (bf16_t*)alloc(HBSZ);
    bf16_t* bu0 = (bf16_t*)alloc((size_t)TSEQ * PSZ * 2);
    bf16_t* bu  = (bf16_t*)alloc((size_t)3 * PSZ * 2);
    bf16_t* rh  = (bf16_t*)alloc((size_t)3 * RHSZ * 2);
    float*  zb  = (float*) alloc((size_t)3 * ZSZ * 4);
    bf16_t* WpIn0 = (bf16_t*)alloc((size_t)18432 * 2);
    bf16_t* WpE10 = (bf16_t*)alloc((size_t)18432 * 2);
    bf16_t* WpE21 = (bf16_t*)alloc((size_t)18432 * 2);
    bf16_t* WpInt[3], *WpG[3], *WpC[3];
    for (int n = 0; n < 3; ++n) WpInt[n] = (bf16_t*)alloc((size_t)9216 * 2);
    for (int n = 0; n < 3; ++n) WpG[n]   = (bf16_t*)alloc((size_t)110592 * 2);
    for (int n = 0; n < 3; ++n) WpC[n]   = (bf16_t*)alloc((size_t)55296 * 2);

    hipMemsetAsync(hF[0], 0, zeroBytes, stream);

    // ---- weight packing (one dispatch) ----
    PackArgs PA{};
    int beg = 0;
    auto seg = [&](int i, const float* src, bf16_t* dst, int Cout, int CinPad, int CinReal) {
        PA.s[i] = {src, dst, Cout / 16, CinPad / 32, CinReal, beg};
        beg += 9 * (CinPad / 32) * (Cout / 16) * 512;
    };
    seg(0, Win0, WpIn0, 32, 64, 3);
    seg(1, We10, WpE10, 32, 64, 64);
    seg(2, We21, WpE21, 32, 64, 64);
    for (int n = 0; n < 3; ++n) seg(3 + n, Wint[n], WpInt[n], 32, 32, 32);
    for (int n = 0; n < 3; ++n) seg(6 + n, Wg[n],   WpG[n],   128, 96, 96);
    for (int n = 0; n < 3; ++n) seg(9 + n, Wc[n],   WpC[n],   64, 96, 96);
    PA.total = beg;
    wpack_all<<<(PA.total + 255) / 256, 256, 0, stream>>>(PA);

    const int GX = 512;   // 8 images x 64 rows, ROWS=1
    const dim3 T(256);

    // ---- node0 bu for ALL 8 timesteps in one dispatch ----
    {
        PJs PJ{};
        for (int t = 0; t < TSEQ; ++t) {
            PJ.u[t].Xf = x; PJ.u[t].t = t;
            PJ.u[t].Wpj = WpIn0; PJ.u[t].bpj = bin0;
            PJ.u[t].Wit = WpInt[0]; PJ.u[t].bit = bint[0];
            PJ.u[t].outB = bu0 + (long)t * PSZ;
        }
        projint_k<1><<<dim3(GX, TSEQ), T, 0, stream>>>(PJ);
    }

    // ---- recurrence: projint -> gates -> cand per step ----
    float*  hFc[3] = {hF[0], hF[1], hF[2]};
    float*  hFn[3] = {hF[3], hF[4], hF[5]};
    bf16_t* hBc[3] = {hB[0], hB[1], hB[2]};
    bf16_t* hBn[3] = {hB[3], hB[4], hB[5]};
    const bf16_t* WpE[2] = {WpE10, WpE21};
    const float*  beE[2] = {be10, be21};

    for (int t = 0; t < PT; ++t) {
        const int nLo = (t > 7) ? (t - 7) : 0;
        const int nHi = (t < 2) ? t : 2;
        const int nAct = nHi - nLo + 1;

        // projint for nodes {1,2} active this step
        if (t >= 1) {
            const int lo = (nLo > 1) ? nLo : 1;
            const int cnt = nHi - lo + 1;
            if (cnt > 0) {
                PJs PJ{};
                for (int i = 0; i < cnt; ++i) {
                    int n = lo + i;
                    PJ.u[i].X = hBc[n - 1];
                    PJ.u[i].Wpj = WpE[n - 1]; PJ.u[i].bpj = beE[n - 1];
                    PJ.u[i].Wit = WpInt[n];   PJ.u[i].bit = bint[n];
                    PJ.u[i].outB = bu + (long)n * PSZ;
                }
                projint_k<0><<<dim3(GX, cnt), T, 0, stream>>>(PJ);
            }
        }
        // gates
        {
            NPs P{};
            for (int i = 0; i < nAct; ++i) {
                int n = nLo + i;
                P.n[i].A0 = (n == 0) ? (bu0 + (long)t * PSZ) : (bu + (long)n * PSZ);
                P.n[i].A1 = hBc[n]; P.n[i].Hb = hBc[n];
                P.n[i].Wp = WpG[n]; P.n[i].bias = bg[n];
                P.n[i].outB = rh + (long)n * RHSZ; P.n[i].outF = zb + (long)n * ZSZ;
            }
            mconv<32, 64, 128, 1, 4><<<dim3(GX, nAct), T, 0, stream>>>(P);
        }
        // cand (+GRU update); final step writes NCHW output directly
        if (t < PT - 1) {
            NPs P{};
            for (int i = 0; i < nAct; ++i) {
                int n = nLo + i;
                P.n[i].A0 = (n == 0) ? (bu0 + (long)t * PSZ) : (bu + (long)n * PSZ);
                P.n[i].A1 = rh + (long)n * RHSZ;
                P.n[i].Zf = zb + (long)n * ZSZ; P.n[i].Hf = hFc[n];
                P.n[i].Wp = WpC[n]; P.n[i].bias = bc[n];
                P.n[i].outB = hBn[n]; P.n[i].outF = hFn[n];
            }
            mconv<32, 64, 64, 2, 4><<<dim3(GX, nAct), T, 0, stream>>>(P);
        } else {
            NPs P{};
            P.n[0].A0 = bu + (long)2 * PSZ;
            P.n[0].A1 = rh + (long)2 * RHSZ;
            P.n[0].Zf = zb + (long)2 * ZSZ; P.n[0].Hf = hFc[2];
            P.n[0].Wp = WpC[2]; P.n[0].bias = bc[2];
            P.n[0].outF = (float*)d_out;
            mconv<32, 64, 64, 3, 4><<<dim3(GX, 1), T, 0, stream>>>(P);
        }
        for (int n = nLo; n <= nHi; ++n) {
            if (t == PT - 1) break;
            float* tf = hFc[n]; hFc[n] = hFn[n]; hFn[n] = tf;
            bf16_t* tb = hBc[n]; hBc[n] = hBn[n]; hBn[n] = tb;
        }
    }
}

// Round 19
// 700.925 us; speedup vs baseline: 1.0896x; 1.0896x over previous
//
#include <hip/hip_runtime.h>
#include <hip/hip_bf16.h>

#define BATCH 8
#define TSEQ 8
#define HH 64
#define WW 64
#define HID 64
#define PT 10   // T + NUM_NODE - 1
#define PIXN 32768   // BATCH*HH*WW

typedef __bf16 bf16_t;
typedef __bf16 bf16x8 __attribute__((ext_vector_type(8)));
typedef float  f32x4  __attribute__((ext_vector_type(4)));

__device__ __forceinline__ float fsigmoid(float v) {
    float e = __builtin_amdgcn_exp2f(-1.4426950408889634f * v);
    return __builtin_amdgcn_rcpf(1.0f + e);
}
__device__ __forceinline__ float ftanh(float v) {
    float e = __builtin_amdgcn_exp2f(2.8853900817779268f * v);   // e^(2v)
    return 1.0f - 2.0f * __builtin_amdgcn_rcpf(1.0f + e);
}

// ---------------------------------------------------------------------------
// Weight pack for 16x16x32 MFMA B-fragments:
//   dst[((chunk*NT16 + nt)*64 + lane)*8 + j],  chunk = tap*KC + kc  (KC=CinPad/32)
//     = w[co = nt*16 + (lane&15)][ci = kc*32 + (lane>>4)*8 + j][tap]
// ---------------------------------------------------------------------------
struct PackSeg { const float* src; bf16_t* dst; int NT16; int KC; int CinReal; int begin; };
struct PackArgs { PackSeg s[12]; int total; };

__global__ void wpack_all(PackArgs P) {
    int idx = blockIdx.x * 256 + threadIdx.x;
    if (idx >= P.total) return;
    int si = 0;
#pragma unroll
    for (int i = 1; i < 12; ++i) if (idx >= P.s[i].begin) si = i;
    PackSeg sg = P.s[si];
    int l = idx - sg.begin;
    int j    = l & 7;
    int lane = (l >> 3) & 63;
    int rest = l >> 9;
    int nt   = rest % sg.NT16;
    int chunk = rest / sg.NT16;
    int kc  = chunk % sg.KC;
    int tap = chunk / sg.KC;
    int co = nt * 16 + (lane & 15);
    int ci = kc * 32 + (lane >> 4) * 8 + j;
    float v = (ci < sg.CinReal) ? sg.src[((long)co * sg.CinReal + ci) * 9 + tap] : 0.0f;
    sg.dst[l] = (bf16_t)v;
}

// ---------------------------------------------------------------------------
// Fused proj+int kernel, ROWS=2 (R17's best measured config; grid 256).
// Phase A: stage input 6 rows x 66 px x 64ch (PSBX 136).
// Phase B: proj conv -> p on 4 rows (2x halo recompute), bf16 into LDS
//          (PSBP 72), borders zeroed (exact zero-pad semantics).
// Phase C: int conv on p -> bu for 2 rows; LDS-bounced coalesced store.
// XIN=1: fuses fp32->bf16 x conversion into staging (bit-identical rounding).
// ---------------------------------------------------------------------------
struct PJ {
    const bf16_t* X;
    const float*  Xf;
    int t;
    const bf16_t* Wpj;
    const float*  bpj;
    const bf16_t* Wit;
    const float*  bit;
    bf16_t* outB;
};
struct PJs { PJ u[8]; };

template <int XIN>
__global__ __launch_bounds__(256, 2) void projint_k(PJs P) {
    constexpr int PSBX = 136;
    constexpr int PSBP = 72;
    constexpr int POFF = 6 * 66 * PSBX;
    __shared__ __align__(16) char smem[6 * 66 * PSBX + 4 * 66 * PSBP];

    const PJ u = P.u[blockIdx.y];
    const int tid = threadIdx.x, lane = tid & 63, w = tid >> 6;
    const int b = blockIdx.x & 7, y0 = (blockIdx.x >> 3) * 2;
    const int l15 = lane & 15, kg = lane >> 4;

    const bf16_t* wpp = u.Wpj + (size_t)(w & 1) * 512 + (size_t)lane * 8;
    bf16x8 ring[4];
#pragma unroll
    for (int i = 0; i < 4; ++i) ring[i] = *(const bf16x8*)(wpp + (size_t)i * 1024);

    if (XIN) {
        // stage from raw fp32 x: 3 real channels, 61 zero
        for (int c = tid; c < 6 * 66; c += 256) {
            int ry = c / 66, px = c - ry * 66;
            int gy = y0 + ry - 2, gx = px - 1;
            bf16x8 v0 = {};
            if ((unsigned)gy < 64u && (unsigned)gx < 64u) {
                long base = ((((long)b * TSEQ + u.t) * 3) * 64 + gy) * 64 + gx;
                v0[0] = (bf16_t)u.Xf[base];
                v0[1] = (bf16_t)u.Xf[base + 4096];
                v0[2] = (bf16_t)u.Xf[base + 8192];
            }
            char* dst = smem + (ry * 66 + px) * PSBX;
            *(bf16x8*)dst = v0;
            bf16x8 zz = {};
#pragma unroll
            for (int c2 = 1; c2 < 8; ++c2) *(bf16x8*)(dst + c2 * 16) = zz;
        }
    } else {
        for (int c = tid; c < 6 * 66 * 8; c += 256) {
            int ry = c / (66 * 8);
            int r  = c - ry * (66 * 8);
            int px = r >> 3, c2 = r & 7;
            int gy = y0 + ry - 2, gx = px - 1;
            bf16x8 v = {};
            if ((unsigned)gy < 64u && (unsigned)gx < 64u)
                v = *(const bf16x8*)(u.X + (((long)b * 64 + gy) * 64 + gx) * 64 + c2 * 8);
            *(bf16x8*)(smem + (ry * 66 + px) * PSBX + c2 * 16) = v;
        }
    }
    if (tid < 32) {
        int row = tid >> 3;
        int col = ((tid >> 2) & 1) ? 65 : 0;
        int chk = tid & 3;
        *(bf16x8*)(smem + POFF + (row * 66 + col) * PSBP + chk * 16) = (bf16x8){};
    }
    if (y0 == 0)
        for (int i = tid; i < 66 * 4; i += 256)
            *(bf16x8*)(smem + POFF + (0 * 66 + (i >> 2)) * PSBP + (i & 3) * 16) = (bf16x8){};
    if (y0 == 62)
        for (int i = tid; i < 66 * 4; i += 256)
            *(bf16x8*)(smem + POFF + (3 * 66 + (i >> 2)) * PSBP + (i & 3) * 16) = (bf16x8){};
    __syncthreads();

    const int ntp = w & 1, mtb = (w >> 1) * 8;
    f32x4 pacc[8];
    {
        float bv = u.bpj[ntp * 16 + l15];
#pragma unroll
        for (int mi = 0; mi < 8; ++mi) pacc[mi] = (f32x4){bv, bv, bv, bv};
    }
#pragma unroll
    for (int ch = 0; ch < 18; ++ch) {
        const int tap = ch >> 1, kc = ch & 1;
        const int ky = tap / 3, kx = tap % 3;
        bf16x8 bcur = ring[ch & 3];
        if (ch + 4 < 18) ring[ch & 3] = *(const bf16x8*)(wpp + (size_t)(ch + 4) * 1024);
#pragma unroll
        for (int mi = 0; mi < 8; ++mi) {
            const int mt = mtb + mi;
            const int prow = mt >> 2, xseg = mt & 3;
            const int addr = ((prow + ky) * 66 + xseg * 16 + l15 + kx) * PSBX
                           + kg * 16 + kc * 64;
            bf16x8 a = *(const bf16x8*)(smem + addr);
            pacc[mi] = __builtin_amdgcn_mfma_f32_16x16x32_bf16(a, bcur, pacc[mi], 0, 0, 0);
        }
    }
    const bf16_t* wpi = u.Wit + (size_t)(w & 1) * 512 + (size_t)lane * 8;
    bf16x8 ring2[4];
#pragma unroll
    for (int i = 0; i < 4; ++i) ring2[i] = *(const bf16x8*)(wpi + (size_t)i * 1024);
#pragma unroll
    for (int mi = 0; mi < 8; ++mi) {
        const int mt = mtb + mi;
        const int prow = mt >> 2, xseg = mt & 3;
        const int gyp = y0 - 1 + prow;
        if (gyp >= 0 && gyp < 64) {
            const int co = ntp * 16 + l15;
#pragma unroll
            for (int reg = 0; reg < 4; ++reg) {
                const int pxi = xseg * 16 + kg * 4 + reg;
                *(bf16_t*)(smem + POFF + (prow * 66 + pxi + 1) * PSBP + co * 2) =
                    (bf16_t)pacc[mi][reg];
            }
        }
    }
    __syncthreads();

    const int nti = w & 1, mtb2 = (w >> 1) * 4;
    f32x4 iacc[4];
    {
        float bv = u.bit[nti * 16 + l15];
#pragma unroll
        for (int mi = 0; mi < 4; ++mi) iacc[mi] = (f32x4){bv, bv, bv, bv};
    }
#pragma unroll
    for (int ch = 0; ch < 9; ++ch) {
        const int ky = ch / 3, kx = ch % 3;
        bf16x8 bcur = ring2[ch & 3];
        if (ch + 4 < 9) ring2[ch & 3] = *(const bf16x8*)(wpi + (size_t)(ch + 4) * 1024);
#pragma unroll
        for (int mi = 0; mi < 4; ++mi) {
            const int mt = mtb2 + mi;
            const int r2 = mt >> 2, xseg = mt & 3;
            const int addr = POFF + ((r2 + ky) * 66 + xseg * 16 + l15 + kx) * PSBP + kg * 16;
            bf16x8 a = *(const bf16x8*)(smem + addr);
            iacc[mi] = __builtin_amdgcn_mfma_f32_16x16x32_bf16(a, bcur, iacc[mi], 0, 0, 0);
        }
    }
    bf16_t* so = (bf16_t*)smem;                 // [128][40]
#pragma unroll
    for (int mi = 0; mi < 4; ++mi) {
        const int mt = mtb2 + mi;
        const int lpx0 = (mt >> 2) * 64 + (mt & 3) * 16 + kg * 4;
        const int co = nti * 16 + l15;
#pragma unroll
        for (int reg = 0; reg < 4; ++reg)
            so[(lpx0 + reg) * 40 + co] = (bf16_t)iacc[mi][reg];
    }
    __syncthreads();
    const long pixbase = ((long)b * 64 + y0) * 64;
    for (int i = tid; i < 128 * 4; i += 256) {
        const int p = i >> 2, cc = (i & 3) * 8;
        *(bf16x8*)(u.outB + (pixbase + p) * 32 + cc) = *(const bf16x8*)(so + p * 40 + cc);
    }
}

// ---------------------------------------------------------------------------
// Gates / cand conv, ROWS=1 (R18's winner: grid 512, up to 4 blocks/CU).
// MODE 1: gates -> rh bf16 + z f32. MODE 2: cand -> h fp32 + h bf16.
// MODE 3: cand final -> NCHW fp32 d_out.
// ---------------------------------------------------------------------------
struct NP {
    const bf16_t* A0;
    const bf16_t* A1;
    const float*  Zf;
    const float*  Hf;
    const bf16_t* Hb;
    const bf16_t* Wp;
    const float*  bias;
    bf16_t* outB;
    float*  outF;
};
struct NPs { NP n[3]; };

template <int CIN0, int CIN1, int COUT, int MODE, int MINW>
__global__ __launch_bounds__(256, MINW) void mconv(NPs P)
{
    constexpr int CIN  = CIN0 + CIN1;
    constexpr int NT16 = COUT / 16;
    constexpr int NCH  = CIN / 8;
    constexpr int KC   = CIN / 32;
    constexpr int NCHUNK = 9 * KC;
    constexpr int PSB  = CIN * 2 + 8;
    constexpr int NT_W = (NT16 > 4) ? NT16 / 4 : 1;   // gates 2, cand 1
    constexpr int NW_N = NT16 / NT_W;                 // 4
    constexpr int MT_W = 4;                           // all waves sweep 4 m-tiles
    constexpr int PF   = 4;
    constexpr int ASMEM = 3 * 66 * PSB;
    constexpr int OSMEM = (MODE == 1 || MODE == 2) ? 64 * 68 * 4 + 64 * 72 * 2
                                                   : 64 * 69 * 4;
    constexpr int SMEM  = (ASMEM > OSMEM) ? ASMEM : OSMEM;

    const NP np   = P.n[blockIdx.y];
    const int tid  = threadIdx.x;
    const int lane = tid & 63;
    const int w    = tid >> 6;
    const int b  = blockIdx.x & 7;
    const int y0 = blockIdx.x >> 3;               // 1 output row

    __shared__ __align__(16) char smem[SMEM];

    const int nt0 = (w % NW_N) * NT_W;
    const int l15 = lane & 15;
    const int kg  = lane >> 4;

    const bf16_t* wp0 = np.Wp + (size_t)nt0 * 512 + (size_t)lane * 8;
    bf16x8 ring[PF][NT_W];
#pragma unroll
    for (int i = 0; i < PF; ++i)
#pragma unroll
        for (int ni = 0; ni < NT_W; ++ni)
            ring[i][ni] = *(const bf16x8*)(wp0 + (size_t)i * (NT16 * 512) + ni * 512);

    for (int c = tid; c < 3 * 66 * NCH; c += 256) {
        int ry = c / (66 * NCH);
        int r  = c - ry * 66 * NCH;
        int px = r / NCH;
        int c2 = r - px * NCH;
        int gy = y0 + ry - 1, gx = px - 1;
        bf16x8 v = {};
        if ((unsigned)gy < 64u && (unsigned)gx < 64u) {
            long pix = ((long)b * 64 + gy) * 64 + gx;
            int ci = c2 * 8;
            if (CIN1 == 0 || ci < CIN0) v = *(const bf16x8*)(np.A0 + pix * CIN0 + ci);
            else                        v = *(const bf16x8*)(np.A1 + pix * CIN1 + (ci - CIN0));
        }
        *(bf16x8*)(smem + (ry * 66 + px) * PSB + c2 * 16) = v;
    }
    __syncthreads();

    int ab[3];
#pragma unroll
    for (int kx = 0; kx < 3; ++kx)
        ab[kx] = (l15 + kx) * PSB + kg * 16;

    f32x4 acc[MT_W][NT_W];
#pragma unroll
    for (int mi = 0; mi < MT_W; ++mi)
#pragma unroll
        for (int ni = 0; ni < NT_W; ++ni) {
            float bv = np.bias[(nt0 + ni) * 16 + l15];
            acc[mi][ni] = (f32x4){bv, bv, bv, bv};
        }

#pragma unroll
    for (int ch = 0; ch < NCHUNK; ++ch) {
        const int tap = ch / KC, kc = ch % KC;
        const int ky = tap / 3, kx = tap % 3;
        bf16x8 bcur[NT_W];
#pragma unroll
        for (int ni = 0; ni < NT_W; ++ni) bcur[ni] = ring[ch % PF][ni];
        if (ch + PF < NCHUNK) {
#pragma unroll
            for (int ni = 0; ni < NT_W; ++ni)
                ring[ch % PF][ni] =
                    *(const bf16x8*)(wp0 + (size_t)(ch + PF) * (NT16 * 512) + ni * 512);
        }
#pragma unroll
        for (int mi = 0; mi < MT_W; ++mi) {
            const int imm = ky * (66 * PSB) + mi * (16 * PSB) + kc * 64;
            bf16x8 a = *(const bf16x8*)(smem + ab[kx] + imm);
#pragma unroll
            for (int ni = 0; ni < NT_W; ++ni)
                acc[mi][ni] = __builtin_amdgcn_mfma_f32_16x16x32_bf16(
                    a, bcur[ni], acc[mi][ni], 0, 0, 0);
        }
    }

    __syncthreads();
    const long pixbase = ((long)b * 64 + y0) * 64;   // 64 contiguous pixels

    if (MODE == 1) {
        bf16_t* srh = (bf16_t*)smem;                         // [64][72] bf16
        float*  sz  = (float*)(smem + 64 * 72 * 2);          // [64][68] f32
#pragma unroll
        for (int mi = 0; mi < MT_W; ++mi) {
            const int lpx0 = mi * 16 + kg * 4;
#pragma unroll
            for (int ni = 0; ni < NT_W; ++ni) {
                const int co = (nt0 + ni) * 16 + l15;
#pragma unroll
                for (int reg = 0; reg < 4; ++reg) {
                    const int lpx = lpx0 + reg;
                    float s = fsigmoid(acc[mi][ni][reg]);
                    if (co < HID) {
                        float hv = (float)np.Hb[(pixbase + lpx) * HID + co];
                        srh[lpx * 72 + co] = (bf16_t)(s * hv);   // rh
                    } else {
                        sz[lpx * 68 + (co - HID)] = s;           // z
                    }
                }
            }
        }
        __syncthreads();
        for (int i = tid; i < 64 * 8; i += 256) {
            const int p = i >> 3, cc = (i & 7) * 8;
            *(bf16x8*)(np.outB + (pixbase + p) * HID + cc) =
                *(const bf16x8*)(srh + p * 72 + cc);
        }
        for (int i = tid; i < 64 * 16; i += 256) {
            const int p = i >> 4, cc = (i & 15) * 4;
            *(f32x4*)(np.outF + (pixbase + p) * HID + cc) =
                *(const f32x4*)(sz + p * 68 + cc);
        }
    } else if (MODE == 2) {
        float*  shf = (float*)smem;                          // [64][68] f32
        bf16_t* shb = (bf16_t*)(smem + 64 * 68 * 4);         // [64][72] bf16
#pragma unroll
        for (int mi = 0; mi < MT_W; ++mi) {
            const int lpx0 = mi * 16 + kg * 4;
#pragma unroll
            for (int ni = 0; ni < NT_W; ++ni) {
                const int co = (nt0 + ni) * 16 + l15;
#pragma unroll
                for (int reg = 0; reg < 4; ++reg) {
                    const int lpx = lpx0 + reg;
                    float cd = ftanh(acc[mi][ni][reg]);
                    float z  = np.Zf[(pixbase + lpx) * HID + co];
                    float ho = np.Hf[(pixbase + lpx) * HID + co];
                    float hn = z * ho + (1.0f - z) * cd;
                    shf[lpx * 68 + co] = hn;
                    shb[lpx * 72 + co] = (bf16_t)hn;
                }
            }
        }
        __syncthreads();
        for (int i = tid; i < 64 * 16; i += 256) {
            const int p = i >> 4, cc = (i & 15) * 4;
            *(f32x4*)(np.outF + (pixbase + p) * HID + cc) =
                *(const f32x4*)(shf + p * 68 + cc);
        }
        for (int i = tid; i < 64 * 8; i += 256) {
            const int p = i >> 3, cc = (i & 7) * 8;
            *(bf16x8*)(np.outB + (pixbase + p) * HID + cc) =
                *(const bf16x8*)(shb + p * 72 + cc);
        }
    } else {   // MODE 3: final cand -> NCHW fp32 output directly
        float* shf = (float*)smem;                           // [64][69] f32
#pragma unroll
        for (int mi = 0; mi < MT_W; ++mi) {
            const int lpx0 = mi * 16 + kg * 4;
#pragma unroll
            for (int ni = 0; ni < NT_W; ++ni) {
                const int co = (nt0 + ni) * 16 + l15;
#pragma unroll
                for (int reg = 0; reg < 4; ++reg) {
                    const int lpx = lpx0 + reg;
                    float cd = ftanh(acc[mi][ni][reg]);
                    float z  = np.Zf[(pixbase + lpx) * HID + co];
                    float ho = np.Hf[(pixbase + lpx) * HID + co];
                    shf[lpx * 69 + co] = z * ho + (1.0f - z) * cd;
                }
            }
        }
        __syncthreads();
        // NCHW: out[((b*64+co)*64 + y0)*64 + x], contiguous in x
        for (int i = tid; i < 64 * 16; i += 256) {
            const int co = i >> 4;
            const int cc = (i & 15) * 4;
            f32x4 v = { shf[(cc + 0) * 69 + co],
                        shf[(cc + 1) * 69 + co],
                        shf[(cc + 2) * 69 + co],
                        shf[(cc + 3) * 69 + co] };
            *(f32x4*)(np.outF + (((long)b * 64 + co) * 64 + y0) * 64 + cc) = v;
        }
    }
}

// ---------------------------------------------------------------------------
extern "C" void kernel_launch(void* const* d_in, const int* in_sizes, int n_in,
                              void* d_out, int out_size, void* d_ws, size_t ws_size,
                              hipStream_t stream) {
    const float* x    = (const float*)d_in[0];
    const float* Win0 = (const float*)d_in[1];
    const float* bin0 = (const float*)d_in[2];
    const float* We10 = (const float*)d_in[3];
    const float* be10 = (const float*)d_in[4];
    const float* We21 = (const float*)d_in[5];
    const float* be21 = (const float*)d_in[6];
    const float* Wint[3] = {(const float*)d_in[7],  (const float*)d_in[13], (const float*)d_in[19]};
    const float* bint[3] = {(const float*)d_in[8],  (const float*)d_in[14], (const float*)d_in[20]};
    const float* Wg[3]   = {(const float*)d_in[9],  (const float*)d_in[15], (const float*)d_in[21]};
    const float* bg[3]   = {(const float*)d_in[10], (const float*)d_in[16], (const float*)d_in[22]};
    const float* Wc[3]   = {(const float*)d_in[11], (const float*)d_in[17], (const float*)d_in[23]};
    const float* bc[3]   = {(const float*)d_in[12], (const float*)d_in[18], (const float*)d_in[24]};
    (void)in_sizes; (void)n_in; (void)out_size; (void)ws_size;

    const long PIX  = (long)PIXN;
    const size_t HFSZ = (size_t)PIX * HID * 4;
    const size_t HBSZ = (size_t)PIX * HID * 2;
    const long PSZ  = PIX * 32;
    const long RHSZ = PIX * HID;
    const long ZSZ  = PIX * HID;

    char* wsb = (char*)d_ws;
    size_t off = 0;
    auto alloc = [&](size_t bytes) -> char* {
        char* q = wsb + off;
        off = (off + bytes + 255) & ~(size_t)255;
        return q;
    };

    // zero-group (contiguous)
    float*  hF[6]; bf16_t* hB[6];
    hF[0] = (float*)alloc(HFSZ); hF[1] = (float*)alloc(HFSZ); hF[2] = (float*)alloc(HFSZ);
    hB[0] = (bf16_t*)alloc(HBSZ); hB[1] = (bf16_t*)alloc(HBSZ); hB[2] = (bf16_t*)alloc(HBSZ);
    const size_t zeroBytes = 3 * HFSZ + 3 * HBSZ;
    hF[3] = (float*)alloc(HFSZ); hF[4] = (float*)alloc(HFSZ); hF[5] = (float*)alloc(HFSZ);
    hB[3] = (bf16_t*)alloc(HBSZ); hB[4] = (bf16_t*)alloc(HBSZ); hB[5] = (bf16_t*)alloc(HBSZ);
    bf16_t* bu0 = (bf16_t*)alloc((size_t)TSEQ * PSZ * 2);
    bf16_t* bu  = (bf16_t*)alloc((size_t)3 * PSZ * 2);
    bf16_t* rh  = (bf16_t*)alloc((size_t)3 * RHSZ * 2);
    float*  zb  = (float*) alloc((size_t)3 * ZSZ * 4);
    bf16_t* WpIn0 = (bf16_t*)alloc((size_t)18432 * 2);
    bf16_t* WpE10 = (bf16_t*)alloc((size_t)18432 * 2);
    bf16_t* WpE21 = (bf16_t*)alloc((size_t)18432 * 2);
    bf16_t* WpInt[3], *WpG[3], *WpC[3];
    for (int n = 0; n < 3; ++n) WpInt[n] = (bf16_t*)alloc((size_t)9216 * 2);
    for (int n = 0; n < 3; ++n) WpG[n]   = (bf16_t*)alloc((size_t)110592 * 2);
    for (int n = 0; n < 3; ++n) WpC[n]   = (bf16_t*)alloc((size_t)55296 * 2);

    hipMemsetAsync(hF[0], 0, zeroBytes, stream);

    // ---- weight packing (one dispatch) ----
    PackArgs PA{};
    int beg = 0;
    auto seg = [&](int i, const float* src, bf16_t* dst, int Cout, int CinPad, int CinReal) {
        PA.s[i] = {src, dst, Cout / 16, CinPad / 32, CinReal, beg};
        beg += 9 * (CinPad / 32) * (Cout / 16) * 512;
    };
    seg(0, Win0, WpIn0, 32, 64, 3);
    seg(1, We10, WpE10, 32, 64, 64);
    seg(2, We21, WpE21, 32, 64, 64);
    for (int n = 0; n < 3; ++n) seg(3 + n, Wint[n], WpInt[n], 32, 32, 32);
    for (int n = 0; n < 3; ++n) seg(6 + n, Wg[n],   WpG[n],   128, 96, 96);
    for (int n = 0; n < 3; ++n) seg(9 + n, Wc[n],   WpC[n],   64, 96, 96);
    PA.total = beg;
    wpack_all<<<(PA.total + 255) / 256, 256, 0, stream>>>(PA);

    const int GXP = 256;   // projint: ROWS=2
    const int GXC = 512;   // gates/cand: ROWS=1
    const dim3 T(256);

    // ---- node0 bu for ALL 8 timesteps in one dispatch (x read + cast fused) ----
    {
        PJs PJ{};
        for (int t = 0; t < TSEQ; ++t) {
            PJ.u[t].Xf = x; PJ.u[t].t = t;
            PJ.u[t].Wpj = WpIn0; PJ.u[t].bpj = bin0;
            PJ.u[t].Wit = WpInt[0]; PJ.u[t].bit = bint[0];
            PJ.u[t].outB = bu0 + (long)t * PSZ;
        }
        projint_k<1><<<dim3(GXP, TSEQ), T, 0, stream>>>(PJ);
    }

    // ---- recurrence: projint -> gates -> cand per step ----
    float*  hFc[3] = {hF[0], hF[1], hF[2]};
    float*  hFn[3] = {hF[3], hF[4], hF[5]};
    bf16_t* hBc[3] = {hB[0], hB[1], hB[2]};
    bf16_t* hBn[3] = {hB[3], hB[4], hB[5]};
    const bf16_t* WpE[2] = {WpE10, WpE21};
    const float*  beE[2] = {be10, be21};

    for (int t = 0; t < PT; ++t) {
        const int nLo = (t > 7) ? (t - 7) : 0;
        const int nHi = (t < 2) ? t : 2;
        const int nAct = nHi - nLo + 1;

        // projint for nodes {1,2} active this step
        if (t >= 1) {
            const int lo = (nLo > 1) ? nLo : 1;
            const int cnt = nHi - lo + 1;
            if (cnt > 0) {
                PJs PJ{};
                for (int i = 0; i < cnt; ++i) {
                    int n = lo + i;
                    PJ.u[i].X = hBc[n - 1];
                    PJ.u[i].Wpj = WpE[n - 1]; PJ.u[i].bpj = beE[n - 1];
                    PJ.u[i].Wit = WpInt[n];   PJ.u[i].bit = bint[n];
                    PJ.u[i].outB = bu + (long)n * PSZ;
                }
                projint_k<0><<<dim3(GXP, cnt), T, 0, stream>>>(PJ);
            }
        }
        // gates
        {
            NPs P{};
            for (int i = 0; i < nAct; ++i) {
                int n = nLo + i;
                P.n[i].A0 = (n == 0) ? (bu0 + (long)t * PSZ) : (bu + (long)n * PSZ);
                P.n[i].A1 = hBc[n]; P.n[i].Hb = hBc[n];
                P.n[i].Wp = WpG[n]; P.n[i].bias = bg[n];
                P.n[i].outB = rh + (long)n * RHSZ; P.n[i].outF = zb + (long)n * ZSZ;
            }
            mconv<32, 64, 128, 1, 4><<<dim3(GXC, nAct), T, 0, stream>>>(P);
        }
        // cand (+GRU update); final step writes NCHW output directly
        if (t < PT - 1) {
            NPs P{};
            for (int i = 0; i < nAct; ++i) {
                int n = nLo + i;
                P.n[i].A0 = (n == 0) ? (bu0 + (long)t * PSZ) : (bu + (long)n * PSZ);
                P.n[i].A1 = rh + (long)n * RHSZ;
                P.n[i].Zf = zb + (long)n * ZSZ; P.n[i].Hf = hFc[n];
                P.n[i].Wp = WpC[n]; P.n[i].bias = bc[n];
                P.n[i].outB = hBn[n]; P.n[i].outF = hFn[n];
            }
            mconv<32, 64, 64, 2, 4><<<dim3(GXC, nAct), T, 0, stream>>>(P);
        } else {
            NPs P{};
            P.n[0].A0 = bu + (long)2 * PSZ;
            P.n[0].A1 = rh + (long)2 * RHSZ;
            P.n[0].Zf = zb + (long)2 * ZSZ; P.n[0].Hf = hFc[2];
            P.n[0].Wp = WpC[2]; P.n[0].bias = bc[2];
            P.n[0].outF = (float*)d_out;
            mconv<32, 64, 64, 3, 4><<<dim3(GXC, 1), T, 0, stream>>>(P);
        }
        for (int n = nLo; n <= nHi; ++n) {
            if (t == PT - 1) break;
            float* tf = hFc[n]; hFc[n] = hFn[n]; hFn[n] = tf;
            bf16_t* tb = hBc[n]; hBc[n] = hBn[n]; hBn[n] = tb;
        }
    }
}

// Round 20
// 686.426 us; speedup vs baseline: 1.1126x; 1.0211x over previous
//
#include <hip/hip_runtime.h>
#include <hip/hip_bf16.h>

#define BATCH 8
#define TSEQ 8
#define HH 64
#define WW 64
#define HID 64
#define PT 10   // T + NUM_NODE - 1
#define PIXN 32768   // BATCH*HH*WW

typedef __bf16 bf16_t;
typedef __bf16 bf16x8 __attribute__((ext_vector_type(8)));
typedef float  f32x4  __attribute__((ext_vector_type(4)));

__device__ __forceinline__ float fsigmoid(float v) {
    float e = __builtin_amdgcn_exp2f(-1.4426950408889634f * v);
    return __builtin_amdgcn_rcpf(1.0f + e);
}
__device__ __forceinline__ float ftanh(float v) {
    float e = __builtin_amdgcn_exp2f(2.8853900817779268f * v);   // e^(2v)
    return 1.0f - 2.0f * __builtin_amdgcn_rcpf(1.0f + e);
}

// ---------------------------------------------------------------------------
// Weight pack for 16x16x32 MFMA B-fragments:
//   dst[((chunk*NT16 + nt)*64 + lane)*8 + j],  chunk = tap*KC + kc  (KC=CinPad/32)
//     = w[co = nt*16 + (lane&15)][ci = kc*32 + (lane>>4)*8 + j][tap]
// ---------------------------------------------------------------------------
struct PackSeg { const float* src; bf16_t* dst; int NT16; int KC; int CinReal; int begin; };
struct PackArgs { PackSeg s[12]; int total; };

__global__ void wpack_all(PackArgs P) {
    int idx = blockIdx.x * 256 + threadIdx.x;
    if (idx >= P.total) return;
    int si = 0;
#pragma unroll
    for (int i = 1; i < 12; ++i) if (idx >= P.s[i].begin) si = i;
    PackSeg sg = P.s[si];
    int l = idx - sg.begin;
    int j    = l & 7;
    int lane = (l >> 3) & 63;
    int rest = l >> 9;
    int nt   = rest % sg.NT16;
    int chunk = rest / sg.NT16;
    int kc  = chunk % sg.KC;
    int tap = chunk / sg.KC;
    int co = nt * 16 + (lane & 15);
    int ci = kc * 32 + (lane >> 4) * 8 + j;
    float v = (ci < sg.CinReal) ? sg.src[((long)co * sg.CinReal + ci) * 9 + tap] : 0.0f;
    sg.dst[l] = (bf16_t)v;
}

// ---------------------------------------------------------------------------
// Fused proj+int kernel, ROWS=2, 512 threads (8 waves) per block.
// Same geometry/math as R19 (bit-identical); work split over 2x the waves:
// proj: 32 (n,m)-tiles over 8 waves = 4 each; int: 16 over 8 = 2 each.
// LDS 73,216 B -> 2 blocks/CU when grid >= 2/CU; waves/CU doubled vs R19.
// XIN=1 fuses fp32->bf16 x conversion into staging (bit-identical rounding).
// ---------------------------------------------------------------------------
struct PJ {
    const bf16_t* X;
    const float*  Xf;
    int t;
    const bf16_t* Wpj;
    const float*  bpj;
    const bf16_t* Wit;
    const float*  bit;
    bf16_t* outB;
};
struct PJs { PJ u[8]; };

template <int XIN>
__global__ __launch_bounds__(512, 2) void projint_k(PJs P) {
    constexpr int PSBX = 136;
    constexpr int PSBP = 72;
    constexpr int POFF = 6 * 66 * PSBX;
    __shared__ __align__(16) char smem[6 * 66 * PSBX + 4 * 66 * PSBP];

    const PJ u = P.u[blockIdx.y];
    const int tid = threadIdx.x, lane = tid & 63, w = tid >> 6;   // w in [0,8)
    const int b = blockIdx.x & 7, y0 = (blockIdx.x >> 3) * 2;
    const int l15 = lane & 15, kg = lane >> 4;

    const bf16_t* wpp = u.Wpj + (size_t)(w & 1) * 512 + (size_t)lane * 8;
    bf16x8 ring[4];
#pragma unroll
    for (int i = 0; i < 4; ++i) ring[i] = *(const bf16x8*)(wpp + (size_t)i * 1024);

    if (XIN) {
        // stage from raw fp32 x: 3 real channels, 61 zero
        for (int c = tid; c < 6 * 66; c += 512) {
            int ry = c / 66, px = c - ry * 66;
            int gy = y0 + ry - 2, gx = px - 1;
            bf16x8 v0 = {};
            if ((unsigned)gy < 64u && (unsigned)gx < 64u) {
                long base = ((((long)b * TSEQ + u.t) * 3) * 64 + gy) * 64 + gx;
                v0[0] = (bf16_t)u.Xf[base];
                v0[1] = (bf16_t)u.Xf[base + 4096];
                v0[2] = (bf16_t)u.Xf[base + 8192];
            }
            char* dst = smem + (ry * 66 + px) * PSBX;
            *(bf16x8*)dst = v0;
            bf16x8 zz = {};
#pragma unroll
            for (int c2 = 1; c2 < 8; ++c2) *(bf16x8*)(dst + c2 * 16) = zz;
        }
    } else {
        for (int c = tid; c < 6 * 66 * 8; c += 512) {
            int ry = c / (66 * 8);
            int r  = c - ry * (66 * 8);
            int px = r >> 3, c2 = r & 7;
            int gy = y0 + ry - 2, gx = px - 1;
            bf16x8 v = {};
            if ((unsigned)gy < 64u && (unsigned)gx < 64u)
                v = *(const bf16x8*)(u.X + (((long)b * 64 + gy) * 64 + gx) * 64 + c2 * 8);
            *(bf16x8*)(smem + (ry * 66 + px) * PSBX + c2 * 16) = v;
        }
    }
    if (tid < 32) {
        int row = tid >> 3;
        int col = ((tid >> 2) & 1) ? 65 : 0;
        int chk = tid & 3;
        *(bf16x8*)(smem + POFF + (row * 66 + col) * PSBP + chk * 16) = (bf16x8){};
    }
    if (y0 == 0)
        for (int i = tid; i < 66 * 4; i += 512)
            *(bf16x8*)(smem + POFF + (0 * 66 + (i >> 2)) * PSBP + (i & 3) * 16) = (bf16x8){};
    if (y0 == 62)
        for (int i = tid; i < 66 * 4; i += 512)
            *(bf16x8*)(smem + POFF + (3 * 66 + (i >> 2)) * PSBP + (i & 3) * 16) = (bf16x8){};
    __syncthreads();

    // ---- proj conv: 32 (n,m)-tiles over 8 waves -> 4 m-tiles each ----
    const int ntp = w & 1, mtb = (w >> 1) * 4;
    f32x4 pacc[4];
    {
        float bv = u.bpj[ntp * 16 + l15];
#pragma unroll
        for (int mi = 0; mi < 4; ++mi) pacc[mi] = (f32x4){bv, bv, bv, bv};
    }
#pragma unroll
    for (int ch = 0; ch < 18; ++ch) {
        const int tap = ch >> 1, kc = ch & 1;
        const int ky = tap / 3, kx = tap % 3;
        bf16x8 bcur = ring[ch & 3];
        if (ch + 4 < 18) ring[ch & 3] = *(const bf16x8*)(wpp + (size_t)(ch + 4) * 1024);
#pragma unroll
        for (int mi = 0; mi < 4; ++mi) {
            const int mt = mtb + mi;
            const int prow = mt >> 2, xseg = mt & 3;
            const int addr = ((prow + ky) * 66 + xseg * 16 + l15 + kx) * PSBX
                           + kg * 16 + kc * 64;
            bf16x8 a = *(const bf16x8*)(smem + addr);
            pacc[mi] = __builtin_amdgcn_mfma_f32_16x16x32_bf16(a, bcur, pacc[mi], 0, 0, 0);
        }
    }
    const bf16_t* wpi = u.Wit + (size_t)(w & 1) * 512 + (size_t)lane * 8;
    bf16x8 ring2[4];
#pragma unroll
    for (int i = 0; i < 4; ++i) ring2[i] = *(const bf16x8*)(wpi + (size_t)i * 1024);
    // write p (bf16) into LDS p-region; out-of-image rows stay zeroed
#pragma unroll
    for (int mi = 0; mi < 4; ++mi) {
        const int mt = mtb + mi;
        const int prow = mt >> 2, xseg = mt & 3;
        const int gyp = y0 - 1 + prow;
        if (gyp >= 0 && gyp < 64) {
            const int co = ntp * 16 + l15;
#pragma unroll
            for (int reg = 0; reg < 4; ++reg) {
                const int pxi = xseg * 16 + kg * 4 + reg;
                *(bf16_t*)(smem + POFF + (prow * 66 + pxi + 1) * PSBP + co * 2) =
                    (bf16_t)pacc[mi][reg];
            }
        }
    }
    __syncthreads();

    // ---- int conv: 16 (n,m)-tiles over 8 waves -> 2 m-tiles each ----
    const int nti = w & 1, mtb2 = (w >> 1) * 2;
    f32x4 iacc[2];
    {
        float bv = u.bit[nti * 16 + l15];
#pragma unroll
        for (int mi = 0; mi < 2; ++mi) iacc[mi] = (f32x4){bv, bv, bv, bv};
    }
#pragma unroll
    for (int ch = 0; ch < 9; ++ch) {
        const int ky = ch / 3, kx = ch % 3;
        bf16x8 bcur = ring2[ch & 3];
        if (ch + 4 < 9) ring2[ch & 3] = *(const bf16x8*)(wpi + (size_t)(ch + 4) * 1024);
#pragma unroll
        for (int mi = 0; mi < 2; ++mi) {
            const int mt = mtb2 + mi;
            const int r2 = mt >> 2, xseg = mt & 3;
            const int addr = POFF + ((r2 + ky) * 66 + xseg * 16 + l15 + kx) * PSBP + kg * 16;
            bf16x8 a = *(const bf16x8*)(smem + addr);
            iacc[mi] = __builtin_amdgcn_mfma_f32_16x16x32_bf16(a, bcur, iacc[mi], 0, 0, 0);
        }
    }
    bf16_t* so = (bf16_t*)smem;                 // [128][40]
#pragma unroll
    for (int mi = 0; mi < 2; ++mi) {
        const int mt = mtb2 + mi;
        const int lpx0 = (mt >> 2) * 64 + (mt & 3) * 16 + kg * 4;
        const int co = nti * 16 + l15;
#pragma unroll
        for (int reg = 0; reg < 4; ++reg)
            so[(lpx0 + reg) * 40 + co] = (bf16_t)iacc[mi][reg];
    }
    __syncthreads();
    const long pixbase = ((long)b * 64 + y0) * 64;
    for (int i = tid; i < 128 * 4; i += 512) {
        const int p = i >> 2, cc = (i & 3) * 8;
        *(bf16x8*)(u.outB + (pixbase + p) * 32 + cc) = *(const bf16x8*)(so + p * 40 + cc);
    }
}

// ---------------------------------------------------------------------------
// Gates / cand conv, ROWS=1 (R19 winner: grid 512, up to 4 blocks/CU).
// MODE 1: gates -> rh bf16 + z f32. MODE 2: cand -> h fp32 + h bf16.
// MODE 3: cand final -> NCHW fp32 d_out.
// ---------------------------------------------------------------------------
struct NP {
    const bf16_t* A0;
    const bf16_t* A1;
    const float*  Zf;
    const float*  Hf;
    const bf16_t* Hb;
    const bf16_t* Wp;
    const float*  bias;
    bf16_t* outB;
    float*  outF;
};
struct NPs { NP n[3]; };

template <int CIN0, int CIN1, int COUT, int MODE, int MINW>
__global__ __launch_bounds__(256, MINW) void mconv(NPs P)
{
    constexpr int CIN  = CIN0 + CIN1;
    constexpr int NT16 = COUT / 16;
    constexpr int NCH  = CIN / 8;
    constexpr int KC   = CIN / 32;
    constexpr int NCHUNK = 9 * KC;
    constexpr int PSB  = CIN * 2 + 8;
    constexpr int NT_W = (NT16 > 4) ? NT16 / 4 : 1;   // gates 2, cand 1
    constexpr int NW_N = NT16 / NT_W;                 // 4
    constexpr int MT_W = 4;                           // all waves sweep 4 m-tiles
    constexpr int PF   = 4;
    constexpr int ASMEM = 3 * 66 * PSB;
    constexpr int OSMEM = (MODE == 1 || MODE == 2) ? 64 * 68 * 4 + 64 * 72 * 2
                                                   : 64 * 69 * 4;
    constexpr int SMEM  = (ASMEM > OSMEM) ? ASMEM : OSMEM;

    const NP np   = P.n[blockIdx.y];
    const int tid  = threadIdx.x;
    const int lane = tid & 63;
    const int w    = tid >> 6;
    const int b  = blockIdx.x & 7;
    const int y0 = blockIdx.x >> 3;               // 1 output row

    __shared__ __align__(16) char smem[SMEM];

    const int nt0 = (w % NW_N) * NT_W;
    const int l15 = lane & 15;
    const int kg  = lane >> 4;

    const bf16_t* wp0 = np.Wp + (size_t)nt0 * 512 + (size_t)lane * 8;
    bf16x8 ring[PF][NT_W];
#pragma unroll
    for (int i = 0; i < PF; ++i)
#pragma unroll
        for (int ni = 0; ni < NT_W; ++ni)
            ring[i][ni] = *(const bf16x8*)(wp0 + (size_t)i * (NT16 * 512) + ni * 512);

    for (int c = tid; c < 3 * 66 * NCH; c += 256) {
        int ry = c / (66 * NCH);
        int r  = c - ry * 66 * NCH;
        int px = r / NCH;
        int c2 = r - px * NCH;
        int gy = y0 + ry - 1, gx = px - 1;
        bf16x8 v = {};
        if ((unsigned)gy < 64u && (unsigned)gx < 64u) {
            long pix = ((long)b * 64 + gy) * 64 + gx;
            int ci = c2 * 8;
            if (CIN1 == 0 || ci < CIN0) v = *(const bf16x8*)(np.A0 + pix * CIN0 + ci);
            else                        v = *(const bf16x8*)(np.A1 + pix * CIN1 + (ci - CIN0));
        }
        *(bf16x8*)(smem + (ry * 66 + px) * PSB + c2 * 16) = v;
    }
    __syncthreads();

    int ab[3];
#pragma unroll
    for (int kx = 0; kx < 3; ++kx)
        ab[kx] = (l15 + kx) * PSB + kg * 16;

    f32x4 acc[MT_W][NT_W];
#pragma unroll
    for (int mi = 0; mi < MT_W; ++mi)
#pragma unroll
        for (int ni = 0; ni < NT_W; ++ni) {
            float bv = np.bias[(nt0 + ni) * 16 + l15];
            acc[mi][ni] = (f32x4){bv, bv, bv, bv};
        }

#pragma unroll
    for (int ch = 0; ch < NCHUNK; ++ch) {
        const int tap = ch / KC, kc = ch % KC;
        const int ky = tap / 3, kx = tap % 3;
        bf16x8 bcur[NT_W];
#pragma unroll
        for (int ni = 0; ni < NT_W; ++ni) bcur[ni] = ring[ch % PF][ni];
        if (ch + PF < NCHUNK) {
#pragma unroll
            for (int ni = 0; ni < NT_W; ++ni)
                ring[ch % PF][ni] =
                    *(const bf16x8*)(wp0 + (size_t)(ch + PF) * (NT16 * 512) + ni * 512);
        }
#pragma unroll
        for (int mi = 0; mi < MT_W; ++mi) {
            const int imm = ky * (66 * PSB) + mi * (16 * PSB) + kc * 64;
            bf16x8 a = *(const bf16x8*)(smem + ab[kx] + imm);
#pragma unroll
            for (int ni = 0; ni < NT_W; ++ni)
                acc[mi][ni] = __builtin_amdgcn_mfma_f32_16x16x32_bf16(
                    a, bcur[ni], acc[mi][ni], 0, 0, 0);
        }
    }

    __syncthreads();
    const long pixbase = ((long)b * 64 + y0) * 64;   // 64 contiguous pixels

    if (MODE == 1) {
        bf16_t* srh = (bf16_t*)smem;                         // [64][72] bf16
        float*  sz  = (float*)(smem + 64 * 72 * 2);          // [64][68] f32
#pragma unroll
        for (int mi = 0; mi < MT_W; ++mi) {
            const int lpx0 = mi * 16 + kg * 4;
#pragma unroll
            for (int ni = 0; ni < NT_W; ++ni) {
                const int co = (nt0 + ni) * 16 + l15;
#pragma unroll
                for (int reg = 0; reg < 4; ++reg) {
                    const int lpx = lpx0 + reg;
                    float s = fsigmoid(acc[mi][ni][reg]);
                    if (co < HID) {
                        float hv = (float)np.Hb[(pixbase + lpx) * HID + co];
                        srh[lpx * 72 + co] = (bf16_t)(s * hv);   // rh
                    } else {
                        sz[lpx * 68 + (co - HID)] = s;           // z
                    }
                }
            }
        }
        __syncthreads();
        for (int i = tid; i < 64 * 8; i += 256) {
            const int p = i >> 3, cc = (i & 7) * 8;
            *(bf16x8*)(np.outB + (pixbase + p) * HID + cc) =
                *(const bf16x8*)(srh + p * 72 + cc);
        }
        for (int i = tid; i < 64 * 16; i += 256) {
            const int p = i >> 4, cc = (i & 15) * 4;
            *(f32x4*)(np.outF + (pixbase + p) * HID + cc) =
                *(const f32x4*)(sz + p * 68 + cc);
        }
    } else if (MODE == 2) {
        float*  shf = (float*)smem;                          // [64][68] f32
        bf16_t* shb = (bf16_t*)(smem + 64 * 68 * 4);         // [64][72] bf16
#pragma unroll
        for (int mi = 0; mi < MT_W; ++mi) {
            const int lpx0 = mi * 16 + kg * 4;
#pragma unroll
            for (int ni = 0; ni < NT_W; ++ni) {
                const int co = (nt0 + ni) * 16 + l15;
#pragma unroll
                for (int reg = 0; reg < 4; ++reg) {
                    const int lpx = lpx0 + reg;
                    float cd = ftanh(acc[mi][ni][reg]);
                    float z  = np.Zf[(pixbase + lpx) * HID + co];
                    float ho = np.Hf[(pixbase + lpx) * HID + co];
                    float hn = z * ho + (1.0f - z) * cd;
                    shf[lpx * 68 + co] = hn;
                    shb[lpx * 72 + co] = (bf16_t)hn;
                }
            }
        }
        __syncthreads();
        for (int i = tid; i < 64 * 16; i += 256) {
            const int p = i >> 4, cc = (i & 15) * 4;
            *(f32x4*)(np.outF + (pixbase + p) * HID + cc) =
                *(const f32x4*)(shf + p * 68 + cc);
        }
        for (int i = tid; i < 64 * 8; i += 256) {
            const int p = i >> 3, cc = (i & 7) * 8;
            *(bf16x8*)(np.outB + (pixbase + p) * HID + cc) =
                *(const bf16x8*)(shb + p * 72 + cc);
        }
    } else {   // MODE 3: final cand -> NCHW fp32 output directly
        float* shf = (float*)smem;                           // [64][69] f32
#pragma unroll
        for (int mi = 0; mi < MT_W; ++mi) {
            const int lpx0 = mi * 16 + kg * 4;
#pragma unroll
            for (int ni = 0; ni < NT_W; ++ni) {
                const int co = (nt0 + ni) * 16 + l15;
#pragma unroll
                for (int reg = 0; reg < 4; ++reg) {
                    const int lpx = lpx0 + reg;
                    float cd = ftanh(acc[mi][ni][reg]);
                    float z  = np.Zf[(pixbase + lpx) * HID + co];
                    float ho = np.Hf[(pixbase + lpx) * HID + co];
                    shf[lpx * 69 + co] = z * ho + (1.0f - z) * cd;
                }
            }
        }
        __syncthreads();
        // NCHW: out[((b*64+co)*64 + y0)*64 + x], contiguous in x
        for (int i = tid; i < 64 * 16; i += 256) {
            const int co = i >> 4;
            const int cc = (i & 15) * 4;
            f32x4 v = { shf[(cc + 0) * 69 + co],
                        shf[(cc + 1) * 69 + co],
                        shf[(cc + 2) * 69 + co],
                        shf[(cc + 3) * 69 + co] };
            *(f32x4*)(np.outF + (((long)b * 64 + co) * 64 + y0) * 64 + cc) = v;
        }
    }
}

// ---------------------------------------------------------------------------
extern "C" void kernel_launch(void* const* d_in, const int* in_sizes, int n_in,
                              void* d_out, int out_size, void* d_ws, size_t ws_size,
                              hipStream_t stream) {
    const float* x    = (const float*)d_in[0];
    const float* Win0 = (const float*)d_in[1];
    const float* bin0 = (const float*)d_in[2];
    const float* We10 = (const float*)d_in[3];
    const float* be10 = (const float*)d_in[4];
    const float* We21 = (const float*)d_in[5];
    const float* be21 = (const float*)d_in[6];
    const float* Wint[3] = {(const float*)d_in[7],  (const float*)d_in[13], (const float*)d_in[19]};
    const float* bint[3] = {(const float*)d_in[8],  (const float*)d_in[14], (const float*)d_in[20]};
    const float* Wg[3]   = {(const float*)d_in[9],  (const float*)d_in[15], (const float*)d_in[21]};
    const float* bg[3]   = {(const float*)d_in[10], (const float*)d_in[16], (const float*)d_in[22]};
    const float* Wc[3]   = {(const float*)d_in[11], (const float*)d_in[17], (const float*)d_in[23]};
    const float* bc[3]   = {(const float*)d_in[12], (const float*)d_in[18], (const float*)d_in[24]};
    (void)in_sizes; (void)n_in; (void)out_size; (void)ws_size;

    const long PIX  = (long)PIXN;
    const size_t HFSZ = (size_t)PIX * HID * 4;
    const size_t HBSZ = (size_t)PIX * HID * 2;
    const long PSZ  = PIX * 32;
    const long RHSZ = PIX * HID;
    const long ZSZ  = PIX * HID;

    char* wsb = (char*)d_ws;
    size_t off = 0;
    auto alloc = [&](size_t bytes) -> char* {
        char* q = wsb + off;
        off = (off + bytes + 255) & ~(size_t)255;
        return q;
    };

    // zero-group (contiguous)
    float*  hF[6]; bf16_t* hB[6];
    hF[0] = (float*)alloc(HFSZ); hF[1] = (float*)alloc(HFSZ); hF[2] = (float*)alloc(HFSZ);
    hB[0] = (bf16_t*)alloc(HBSZ); hB[1] = (bf16_t*)alloc(HBSZ); hB[2] = (bf16_t*)alloc(HBSZ);
    const size_t zeroBytes = 3 * HFSZ + 3 * HBSZ;
    hF[3] = (float*)alloc(HFSZ); hF[4] = (float*)alloc(HFSZ); hF[5] = (float*)alloc(HFSZ);
    hB[3] = (bf16_t*)alloc(HBSZ); hB[4] = (bf16_t*)alloc(HBSZ); hB[5] = (bf16_t*)alloc(HBSZ);
    bf16_t* bu0 = (bf16_t*)alloc((size_t)TSEQ * PSZ * 2);
    bf16_t* bu  = (bf16_t*)alloc((size_t)3 * PSZ * 2);
    bf16_t* rh  = (bf16_t*)alloc((size_t)3 * RHSZ * 2);
    float*  zb  = (float*) alloc((size_t)3 * ZSZ * 4);
    bf16_t* WpIn0 = (bf16_t*)alloc((size_t)18432 * 2);
    bf16_t* WpE10 = (bf16_t*)alloc((size_t)18432 * 2);
    bf16_t* WpE21 = (bf16_t*)alloc((size_t)18432 * 2);
    bf16_t* WpInt[3], *WpG[3], *WpC[3];
    for (int n = 0; n < 3; ++n) WpInt[n] = (bf16_t*)alloc((size_t)9216 * 2);
    for (int n = 0; n < 3; ++n) WpG[n]   = (bf16_t*)alloc((size_t)110592 * 2);
    for (int n = 0; n < 3; ++n) WpC[n]   = (bf16_t*)alloc((size_t)55296 * 2);

    hipMemsetAsync(hF[0], 0, zeroBytes, stream);

    // ---- weight packing (one dispatch) ----
    PackArgs PA{};
    int beg = 0;
    auto seg = [&](int i, const float* src, bf16_t* dst, int Cout, int CinPad, int CinReal) {
        PA.s[i] = {src, dst, Cout / 16, CinPad / 32, CinReal, beg};
        beg += 9 * (CinPad / 32) * (Cout / 16) * 512;
    };
    seg(0, Win0, WpIn0, 32, 64, 3);
    seg(1, We10, WpE10, 32, 64, 64);
    seg(2, We21, WpE21, 32, 64, 64);
    for (int n = 0; n < 3; ++n) seg(3 + n, Wint[n], WpInt[n], 32, 32, 32);
    for (int n = 0; n < 3; ++n) seg(6 + n, Wg[n],   WpG[n],   128, 96, 96);
    for (int n = 0; n < 3; ++n) seg(9 + n, Wc[n],   WpC[n],   64, 96, 96);
    PA.total = beg;
    wpack_all<<<(PA.total + 255) / 256, 256, 0, stream>>>(PA);

    const int GXP = 256;   // projint: ROWS=2, 512-thr blocks
    const int GXC = 512;   // gates/cand: ROWS=1, 256-thr blocks
    const dim3 TP(512), TC(256);

    // ---- node0 bu for ALL 8 timesteps in one dispatch (x read + cast fused) ----
    {
        PJs PJ{};
        for (int t = 0; t < TSEQ; ++t) {
            PJ.u[t].Xf = x; PJ.u[t].t = t;
            PJ.u[t].Wpj = WpIn0; PJ.u[t].bpj = bin0;
            PJ.u[t].Wit = WpInt[0]; PJ.u[t].bit = bint[0];
            PJ.u[t].outB = bu0 + (long)t * PSZ;
        }
        projint_k<1><<<dim3(GXP, TSEQ), TP, 0, stream>>>(PJ);
    }

    // ---- recurrence: projint -> gates -> cand per step ----
    float*  hFc[3] = {hF[0], hF[1], hF[2]};
    float*  hFn[3] = {hF[3], hF[4], hF[5]};
    bf16_t* hBc[3] = {hB[0], hB[1], hB[2]};
    bf16_t* hBn[3] = {hB[3], hB[4], hB[5]};
    const bf16_t* WpE[2] = {WpE10, WpE21};
    const float*  beE[2] = {be10, be21};

    for (int t = 0; t < PT; ++t) {
        const int nLo = (t > 7) ? (t - 7) : 0;
        const int nHi = (t < 2) ? t : 2;
        const int nAct = nHi - nLo + 1;

        // projint for nodes {1,2} active this step
        if (t >= 1) {
            const int lo = (nLo > 1) ? nLo : 1;
            const int cnt = nHi - lo + 1;
            if (cnt > 0) {
                PJs PJ{};
                for (int i = 0; i < cnt; ++i) {
                    int n = lo + i;
                    PJ.u[i].X = hBc[n - 1];
                    PJ.u[i].Wpj = WpE[n - 1]; PJ.u[i].bpj = beE[n - 1];
                    PJ.u[i].Wit = WpInt[n];   PJ.u[i].bit = bint[n];
                    PJ.u[i].outB = bu + (long)n * PSZ;
                }
                projint_k<0><<<dim3(GXP, cnt), TP, 0, stream>>>(PJ);
            }
        }
        // gates
        {
            NPs P{};
            for (int i = 0; i < nAct; ++i) {
                int n = nLo + i;
                P.n[i].A0 = (n == 0) ? (bu0 + (long)t * PSZ) : (bu + (long)n * PSZ);
                P.n[i].A1 = hBc[n]; P.n[i].Hb = hBc[n];
                P.n[i].Wp = WpG[n]; P.n[i].bias = bg[n];
                P.n[i].outB = rh + (long)n * RHSZ; P.n[i].outF = zb + (long)n * ZSZ;
            }
            mconv<32, 64, 128, 1, 4><<<dim3(GXC, nAct), TC, 0, stream>>>(P);
        }
        // cand (+GRU update); final step writes NCHW output directly
        if (t < PT - 1) {
            NPs P{};
            for (int i = 0; i < nAct; ++i) {
                int n = nLo + i;
                P.n[i].A0 = (n == 0) ? (bu0 + (long)t * PSZ) : (bu + (long)n * PSZ);
                P.n[i].A1 = rh + (long)n * RHSZ;
                P.n[i].Zf = zb + (long)n * ZSZ; P.n[i].Hf = hFc[n];
                P.n[i].Wp = WpC[n]; P.n[i].bias = bc[n];
                P.n[i].outB = hBn[n]; P.n[i].outF = hFn[n];
            }
            mconv<32, 64, 64, 2, 4><<<dim3(GXC, nAct), TC, 0, stream>>>(P);
        } else {
            NPs P{};
            P.n[0].A0 = bu + (long)2 * PSZ;
            P.n[0].A1 = rh + (long)2 * RHSZ;
            P.n[0].Zf = zb + (long)2 * ZSZ; P.n[0].Hf = hFc[2];
            P.n[0].Wp = WpC[2]; P.n[0].bias = bc[2];
            P.n[0].outF = (float*)d_out;
            mconv<32, 64, 64, 3, 4><<<dim3(GXC, 1), TC, 0, stream>>>(P);
        }
        for (int n = nLo; n <= nHi; ++n) {
            if (t == PT - 1) break;
            float* tf = hFc[n]; hFc[n] = hFn[n]; hFn[n] = tf;
            bf16_t* tb = hBc[n]; hBc[n] = hBn[n]; hBn[n] = tb;
        }
    }
}

// Round 21
// 642.047 us; speedup vs baseline: 1.1895x; 1.0691x over previous
//
#include <hip/hip_runtime.h>
#include <hip/hip_bf16.h>

#define BATCH 8
#define TSEQ 8
#define HH 64
#define WW 64
#define HID 64
#define PT 10   // T + NUM_NODE - 1
#define PIXN 32768   // BATCH*HH*WW

typedef __bf16 bf16_t;
typedef __bf16 bf16x8 __attribute__((ext_vector_type(8)));
typedef float  f32x4  __attribute__((ext_vector_type(4)));

__device__ __forceinline__ float fsigmoid(float v) {
    float e = __builtin_amdgcn_exp2f(-1.4426950408889634f * v);
    return __builtin_amdgcn_rcpf(1.0f + e);
}
__device__ __forceinline__ float ftanh(float v) {
    float e = __builtin_amdgcn_exp2f(2.8853900817779268f * v);   // e^(2v)
    return 1.0f - 2.0f * __builtin_amdgcn_rcpf(1.0f + e);
}

// ---------------------------------------------------------------------------
// Weight pack for 16x16x32 MFMA B-fragments:
//   dst[((chunk*NT16 + nt)*64 + lane)*8 + j],  chunk = tap*KC + kc  (KC=CinPad/32)
//     = w[co = nt*16 + (lane&15)][ci = kc*32 + (lane>>4)*8 + j][tap]
// ---------------------------------------------------------------------------
struct PackSeg { const float* src; bf16_t* dst; int NT16; int KC; int CinReal; int begin; };
struct PackArgs { PackSeg s[12]; int total; };

__global__ void wpack_all(PackArgs P) {
    int idx = blockIdx.x * 256 + threadIdx.x;
    if (idx >= P.total) return;
    int si = 0;
#pragma unroll
    for (int i = 1; i < 12; ++i) if (idx >= P.s[i].begin) si = i;
    PackSeg sg = P.s[si];
    int l = idx - sg.begin;
    int j    = l & 7;
    int lane = (l >> 3) & 63;
    int rest = l >> 9;
    int nt   = rest % sg.NT16;
    int chunk = rest / sg.NT16;
    int kc  = chunk % sg.KC;
    int tap = chunk / sg.KC;
    int co = nt * 16 + (lane & 15);
    int ci = kc * 32 + (lane >> 4) * 8 + j;
    float v = (ci < sg.CinReal) ? sg.src[((long)co * sg.CinReal + ci) * 9 + tap] : 0.0f;
    sg.dst[l] = (bf16_t)v;
}

// ---------------------------------------------------------------------------
// Fused proj+int kernel, ROWS=2, 512 threads (8 waves) per block (R20).
// XIN=1 fuses fp32->bf16 x conversion into staging (bit-identical rounding).
// ---------------------------------------------------------------------------
struct PJ {
    const bf16_t* X;
    const float*  Xf;
    int t;
    const bf16_t* Wpj;
    const float*  bpj;
    const bf16_t* Wit;
    const float*  bit;
    bf16_t* outB;
};
struct PJs { PJ u[8]; };

template <int XIN>
__global__ __launch_bounds__(512, 2) void projint_k(PJs P) {
    constexpr int PSBX = 136;
    constexpr int PSBP = 72;
    constexpr int POFF = 6 * 66 * PSBX;
    __shared__ __align__(16) char smem[6 * 66 * PSBX + 4 * 66 * PSBP];

    const PJ u = P.u[blockIdx.y];
    const int tid = threadIdx.x, lane = tid & 63, w = tid >> 6;   // w in [0,8)
    const int b = blockIdx.x & 7, y0 = (blockIdx.x >> 3) * 2;
    const int l15 = lane & 15, kg = lane >> 4;

    const bf16_t* wpp = u.Wpj + (size_t)(w & 1) * 512 + (size_t)lane * 8;
    bf16x8 ring[4];
#pragma unroll
    for (int i = 0; i < 4; ++i) ring[i] = *(const bf16x8*)(wpp + (size_t)i * 1024);

    if (XIN) {
        for (int c = tid; c < 6 * 66; c += 512) {
            int ry = c / 66, px = c - ry * 66;
            int gy = y0 + ry - 2, gx = px - 1;
            bf16x8 v0 = {};
            if ((unsigned)gy < 64u && (unsigned)gx < 64u) {
                long base = ((((long)b * TSEQ + u.t) * 3) * 64 + gy) * 64 + gx;
                v0[0] = (bf16_t)u.Xf[base];
                v0[1] = (bf16_t)u.Xf[base + 4096];
                v0[2] = (bf16_t)u.Xf[base + 8192];
            }
            char* dst = smem + (ry * 66 + px) * PSBX;
            *(bf16x8*)dst = v0;
            bf16x8 zz = {};
#pragma unroll
            for (int c2 = 1; c2 < 8; ++c2) *(bf16x8*)(dst + c2 * 16) = zz;
        }
    } else {
        for (int c = tid; c < 6 * 66 * 8; c += 512) {
            int ry = c / (66 * 8);
            int r  = c - ry * (66 * 8);
            int px = r >> 3, c2 = r & 7;
            int gy = y0 + ry - 2, gx = px - 1;
            bf16x8 v = {};
            if ((unsigned)gy < 64u && (unsigned)gx < 64u)
                v = *(const bf16x8*)(u.X + (((long)b * 64 + gy) * 64 + gx) * 64 + c2 * 8);
            *(bf16x8*)(smem + (ry * 66 + px) * PSBX + c2 * 16) = v;
        }
    }
    if (tid < 32) {
        int row = tid >> 3;
        int col = ((tid >> 2) & 1) ? 65 : 0;
        int chk = tid & 3;
        *(bf16x8*)(smem + POFF + (row * 66 + col) * PSBP + chk * 16) = (bf16x8){};
    }
    if (y0 == 0)
        for (int i = tid; i < 66 * 4; i += 512)
            *(bf16x8*)(smem + POFF + (0 * 66 + (i >> 2)) * PSBP + (i & 3) * 16) = (bf16x8){};
    if (y0 == 62)
        for (int i = tid; i < 66 * 4; i += 512)
            *(bf16x8*)(smem + POFF + (3 * 66 + (i >> 2)) * PSBP + (i & 3) * 16) = (bf16x8){};
    __syncthreads();

    // ---- proj conv: 32 (n,m)-tiles over 8 waves -> 4 m-tiles each ----
    const int ntp = w & 1, mtb = (w >> 1) * 4;
    f32x4 pacc[4];
    {
        float bv = u.bpj[ntp * 16 + l15];
#pragma unroll
        for (int mi = 0; mi < 4; ++mi) pacc[mi] = (f32x4){bv, bv, bv, bv};
    }
#pragma unroll
    for (int ch = 0; ch < 18; ++ch) {
        const int tap = ch >> 1, kc = ch & 1;
        const int ky = tap / 3, kx = tap % 3;
        bf16x8 bcur = ring[ch & 3];
        if (ch + 4 < 18) ring[ch & 3] = *(const bf16x8*)(wpp + (size_t)(ch + 4) * 1024);
#pragma unroll
        for (int mi = 0; mi < 4; ++mi) {
            const int mt = mtb + mi;
            const int prow = mt >> 2, xseg = mt & 3;
            const int addr = ((prow + ky) * 66 + xseg * 16 + l15 + kx) * PSBX
                           + kg * 16 + kc * 64;
            bf16x8 a = *(const bf16x8*)(smem + addr);
            pacc[mi] = __builtin_amdgcn_mfma_f32_16x16x32_bf16(a, bcur, pacc[mi], 0, 0, 0);
        }
    }
    const bf16_t* wpi = u.Wit + (size_t)(w & 1) * 512 + (size_t)lane * 8;
    bf16x8 ring2[4];
#pragma unroll
    for (int i = 0; i < 4; ++i) ring2[i] = *(const bf16x8*)(wpi + (size_t)i * 1024);
#pragma unroll
    for (int mi = 0; mi < 4; ++mi) {
        const int mt = mtb + mi;
        const int prow = mt >> 2, xseg = mt & 3;
        const int gyp = y0 - 1 + prow;
        if (gyp >= 0 && gyp < 64) {
            const int co = ntp * 16 + l15;
#pragma unroll
            for (int reg = 0; reg < 4; ++reg) {
                const int pxi = xseg * 16 + kg * 4 + reg;
                *(bf16_t*)(smem + POFF + (prow * 66 + pxi + 1) * PSBP + co * 2) =
                    (bf16_t)pacc[mi][reg];
            }
        }
    }
    __syncthreads();

    // ---- int conv: 16 (n,m)-tiles over 8 waves -> 2 m-tiles each ----
    const int nti = w & 1, mtb2 = (w >> 1) * 2;
    f32x4 iacc[2];
    {
        float bv = u.bit[nti * 16 + l15];
#pragma unroll
        for (int mi = 0; mi < 2; ++mi) iacc[mi] = (f32x4){bv, bv, bv, bv};
    }
#pragma unroll
    for (int ch = 0; ch < 9; ++ch) {
        const int ky = ch / 3, kx = ch % 3;
        bf16x8 bcur = ring2[ch & 3];
        if (ch + 4 < 9) ring2[ch & 3] = *(const bf16x8*)(wpi + (size_t)(ch + 4) * 1024);
#pragma unroll
        for (int mi = 0; mi < 2; ++mi) {
            const int mt = mtb2 + mi;
            const int r2 = mt >> 2, xseg = mt & 3;
            const int addr = POFF + ((r2 + ky) * 66 + xseg * 16 + l15 + kx) * PSBP + kg * 16;
            bf16x8 a = *(const bf16x8*)(smem + addr);
            iacc[mi] = __builtin_amdgcn_mfma_f32_16x16x32_bf16(a, bcur, iacc[mi], 0, 0, 0);
        }
    }
    bf16_t* so = (bf16_t*)smem;                 // [128][40]
#pragma unroll
    for (int mi = 0; mi < 2; ++mi) {
        const int mt = mtb2 + mi;
        const int lpx0 = (mt >> 2) * 64 + (mt & 3) * 16 + kg * 4;
        const int co = nti * 16 + l15;
#pragma unroll
        for (int reg = 0; reg < 4; ++reg)
            so[(lpx0 + reg) * 40 + co] = (bf16_t)iacc[mi][reg];
    }
    __syncthreads();
    const long pixbase = ((long)b * 64 + y0) * 64;
    for (int i = tid; i < 128 * 4; i += 512) {
        const int p = i >> 2, cc = (i & 3) * 8;
        *(bf16x8*)(u.outB + (pixbase + p) * 32 + cc) = *(const bf16x8*)(so + p * 40 + cc);
    }
}

// ---------------------------------------------------------------------------
// Gates / cand conv, ROWS=1, WAVES-templated (R21: 512 threads, 8 waves).
// Wave tiling: NW_N = min(NT16, WAVES) n-tile owners; wave groups split the
// 4 m-tiles. Same chunk order per output -> bit-identical results.
// MODE 1: gates -> rh bf16 + z f32. MODE 2: cand -> h fp32 + h bf16.
// MODE 3: cand final -> NCHW fp32 d_out.
// ---------------------------------------------------------------------------
struct NP {
    const bf16_t* A0;
    const bf16_t* A1;
    const float*  Zf;
    const float*  Hf;
    const bf16_t* Hb;
    const bf16_t* Wp;
    const float*  bias;
    bf16_t* outB;
    float*  outF;
};
struct NPs { NP n[3]; };

template <int CIN0, int CIN1, int COUT, int MODE, int WAVES, int MINW>
__global__ __launch_bounds__(WAVES * 64, MINW) void mconv(NPs P)
{
    constexpr int CIN  = CIN0 + CIN1;
    constexpr int NT16 = COUT / 16;
    constexpr int NCH  = CIN / 8;
    constexpr int KC   = CIN / 32;
    constexpr int NCHUNK = 9 * KC;
    constexpr int PSB  = CIN * 2 + 8;
    constexpr int NTHR = WAVES * 64;
    constexpr int NW_N = (NT16 < WAVES) ? NT16 : WAVES;
    constexpr int NT_W = NT16 / NW_N;
    constexpr int NW_M = WAVES / NW_N;
    constexpr int MT_W = 4 / NW_M;                // m16 tiles per wave (4 total)
    constexpr int PF   = 4;
    constexpr int ASMEM = 3 * 66 * PSB;
    constexpr int OSMEM = (MODE == 1 || MODE == 2) ? 64 * 68 * 4 + 64 * 72 * 2
                                                   : 64 * 69 * 4;
    constexpr int SMEM  = (ASMEM > OSMEM) ? ASMEM : OSMEM;
    static_assert(4 % NW_M == 0, "bad wave geometry");

    const NP np   = P.n[blockIdx.y];
    const int tid  = threadIdx.x;
    const int lane = tid & 63;
    const int w    = tid >> 6;
    const int b  = blockIdx.x & 7;
    const int y0 = blockIdx.x >> 3;               // 1 output row

    __shared__ __align__(16) char smem[SMEM];

    const int nt0 = (w % NW_N) * NT_W;
    const int mt0 = (w / NW_N) * MT_W;
    const int l15 = lane & 15;
    const int kg  = lane >> 4;

    const bf16_t* wp0 = np.Wp + (size_t)nt0 * 512 + (size_t)lane * 8;
    bf16x8 ring[PF][NT_W];
#pragma unroll
    for (int i = 0; i < PF; ++i)
#pragma unroll
        for (int ni = 0; ni < NT_W; ++ni)
            ring[i][ni] = *(const bf16x8*)(wp0 + (size_t)i * (NT16 * 512) + ni * 512);

    for (int c = tid; c < 3 * 66 * NCH; c += NTHR) {
        int ry = c / (66 * NCH);
        int r  = c - ry * 66 * NCH;
        int px = r / NCH;
        int c2 = r - px * NCH;
        int gy = y0 + ry - 1, gx = px - 1;
        bf16x8 v = {};
        if ((unsigned)gy < 64u && (unsigned)gx < 64u) {
            long pix = ((long)b * 64 + gy) * 64 + gx;
            int ci = c2 * 8;
            if (CIN1 == 0 || ci < CIN0) v = *(const bf16x8*)(np.A0 + pix * CIN0 + ci);
            else                        v = *(const bf16x8*)(np.A1 + pix * CIN1 + (ci - CIN0));
        }
        *(bf16x8*)(smem + (ry * 66 + px) * PSB + c2 * 16) = v;
    }
    __syncthreads();

    int ab[3];
#pragma unroll
    for (int kx = 0; kx < 3; ++kx)
        ab[kx] = (l15 + kx) * PSB + kg * 16;

    f32x4 acc[MT_W][NT_W];
#pragma unroll
    for (int mi = 0; mi < MT_W; ++mi)
#pragma unroll
        for (int ni = 0; ni < NT_W; ++ni) {
            float bv = np.bias[(nt0 + ni) * 16 + l15];
            acc[mi][ni] = (f32x4){bv, bv, bv, bv};
        }

#pragma unroll
    for (int ch = 0; ch < NCHUNK; ++ch) {
        const int tap = ch / KC, kc = ch % KC;
        const int ky = tap / 3, kx = tap % 3;
        bf16x8 bcur[NT_W];
#pragma unroll
        for (int ni = 0; ni < NT_W; ++ni) bcur[ni] = ring[ch % PF][ni];
        if (ch + PF < NCHUNK) {
#pragma unroll
            for (int ni = 0; ni < NT_W; ++ni)
                ring[ch % PF][ni] =
                    *(const bf16x8*)(wp0 + (size_t)(ch + PF) * (NT16 * 512) + ni * 512);
        }
#pragma unroll
        for (int mi = 0; mi < MT_W; ++mi) {
            const int imm = ky * (66 * PSB) + (mt0 + mi) * (16 * PSB) + kc * 64;
            bf16x8 a = *(const bf16x8*)(smem + ab[kx] + imm);
#pragma unroll
            for (int ni = 0; ni < NT_W; ++ni)
                acc[mi][ni] = __builtin_amdgcn_mfma_f32_16x16x32_bf16(
                    a, bcur[ni], acc[mi][ni], 0, 0, 0);
        }
    }

    __syncthreads();
    const long pixbase = ((long)b * 64 + y0) * 64;   // 64 contiguous pixels

    if (MODE == 1) {
        bf16_t* srh = (bf16_t*)smem;                         // [64][72] bf16
        float*  sz  = (float*)(smem + 64 * 72 * 2);          // [64][68] f32
#pragma unroll
        for (int mi = 0; mi < MT_W; ++mi) {
            const int lpx0 = (mt0 + mi) * 16 + kg * 4;
#pragma unroll
            for (int ni = 0; ni < NT_W; ++ni) {
                const int co = (nt0 + ni) * 16 + l15;
#pragma unroll
                for (int reg = 0; reg < 4; ++reg) {
                    const int lpx = lpx0 + reg;
                    float s = fsigmoid(acc[mi][ni][reg]);
                    if (co < HID) {
                        float hv = (float)np.Hb[(pixbase + lpx) * HID + co];
                        srh[lpx * 72 + co] = (bf16_t)(s * hv);   // rh
                    } else {
                        sz[lpx * 68 + (co - HID)] = s;           // z
                    }
                }
            }
        }
        __syncthreads();
        for (int i = tid; i < 64 * 8; i += NTHR) {
            const int p = i >> 3, cc = (i & 7) * 8;
            *(bf16x8*)(np.outB + (pixbase + p) * HID + cc) =
                *(const bf16x8*)(srh + p * 72 + cc);
        }
        for (int i = tid; i < 64 * 16; i += NTHR) {
            const int p = i >> 4, cc = (i & 15) * 4;
            *(f32x4*)(np.outF + (pixbase + p) * HID + cc) =
                *(const f32x4*)(sz + p * 68 + cc);
        }
    } else if (MODE == 2) {
        float*  shf = (float*)smem;                          // [64][68] f32
        bf16_t* shb = (bf16_t*)(smem + 64 * 68 * 4);         // [64][72] bf16
#pragma unroll
        for (int mi = 0; mi < MT_W; ++mi) {
            const int lpx0 = (mt0 + mi) * 16 + kg * 4;
#pragma unroll
            for (int ni = 0; ni < NT_W; ++ni) {
                const int co = (nt0 + ni) * 16 + l15;
#pragma unroll
                for (int reg = 0; reg < 4; ++reg) {
                    const int lpx = lpx0 + reg;
                    float cd = ftanh(acc[mi][ni][reg]);
                    float z  = np.Zf[(pixbase + lpx) * HID + co];
                    float ho = np.Hf[(pixbase + lpx) * HID + co];
                    float hn = z * ho + (1.0f - z) * cd;
                    shf[lpx * 68 + co] = hn;
                    shb[lpx * 72 + co] = (bf16_t)hn;
                }
            }
        }
        __syncthreads();
        for (int i = tid; i < 64 * 16; i += NTHR) {
            const int p = i >> 4, cc = (i & 15) * 4;
            *(f32x4*)(np.outF + (pixbase + p) * HID + cc) =
                *(const f32x4*)(shf + p * 68 + cc);
        }
        for (int i = tid; i < 64 * 8; i += NTHR) {
            const int p = i >> 3, cc = (i & 7) * 8;
            *(bf16x8*)(np.outB + (pixbase + p) * HID + cc) =
                *(const bf16x8*)(shb + p * 72 + cc);
        }
    } else {   // MODE 3: final cand -> NCHW fp32 output directly
        float* shf = (float*)smem;                           // [64][69] f32
#pragma unroll
        for (int mi = 0; mi < MT_W; ++mi) {
            const int lpx0 = (mt0 + mi) * 16 + kg * 4;
#pragma unroll
            for (int ni = 0; ni < NT_W; ++ni) {
                const int co = (nt0 + ni) * 16 + l15;
#pragma unroll
                for (int reg = 0; reg < 4; ++reg) {
                    const int lpx = lpx0 + reg;
                    float cd = ftanh(acc[mi][ni][reg]);
                    float z  = np.Zf[(pixbase + lpx) * HID + co];
                    float ho = np.Hf[(pixbase + lpx) * HID + co];
                    shf[lpx * 69 + co] = z * ho + (1.0f - z) * cd;
                }
            }
        }
        __syncthreads();
        // NCHW: out[((b*64+co)*64 + y0)*64 + x], contiguous in x
        for (int i = tid; i < 64 * 16; i += NTHR) {
            const int co = i >> 4;
            const int cc = (i & 15) * 4;
            f32x4 v = { shf[(cc + 0) * 69 + co],
                        shf[(cc + 1) * 69 + co],
                        shf[(cc + 2) * 69 + co],
                        shf[(cc + 3) * 69 + co] };
            *(f32x4*)(np.outF + (((long)b * 64 + co) * 64 + y0) * 64 + cc) = v;
        }
    }
}

// ---------------------------------------------------------------------------
extern "C" void kernel_launch(void* const* d_in, const int* in_sizes, int n_in,
                              void* d_out, int out_size, void* d_ws, size_t ws_size,
                              hipStream_t stream) {
    const float* x    = (const float*)d_in[0];
    const float* Win0 = (const float*)d_in[1];
    const float* bin0 = (const float*)d_in[2];
    const float* We10 = (const float*)d_in[3];
    const float* be10 = (const float*)d_in[4];
    const float* We21 = (const float*)d_in[5];
    const float* be21 = (const float*)d_in[6];
    const float* Wint[3] = {(const float*)d_in[7],  (const float*)d_in[13], (const float*)d_in[19]};
    const float* bint[3] = {(const float*)d_in[8],  (const float*)d_in[14], (const float*)d_in[20]};
    const float* Wg[3]   = {(const float*)d_in[9],  (const float*)d_in[15], (const float*)d_in[21]};
    const float* bg[3]   = {(const float*)d_in[10], (const float*)d_in[16], (const float*)d_in[22]};
    const float* Wc[3]   = {(const float*)d_in[11], (const float*)d_in[17], (const float*)d_in[23]};
    const float* bc[3]   = {(const float*)d_in[12], (const float*)d_in[18], (const float*)d_in[24]};
    (void)in_sizes; (void)n_in; (void)out_size; (void)ws_size;

    const long PIX  = (long)PIXN;
    const size_t HFSZ = (size_t)PIX * HID * 4;
    const size_t HBSZ = (size_t)PIX * HID * 2;
    const long PSZ  = PIX * 32;
    const long RHSZ = PIX * HID;
    const long ZSZ  = PIX * HID;

    char* wsb = (char*)d_ws;
    size_t off = 0;
    auto alloc = [&](size_t bytes) -> char* {
        char* q = wsb + off;
        off = (off + bytes + 255) & ~(size_t)255;
        return q;
    };

    // zero-group (contiguous)
    float*  hF[6]; bf16_t* hB[6];
    hF[0] = (float*)alloc(HFSZ); hF[1] = (float*)alloc(HFSZ); hF[2] = (float*)alloc(HFSZ);
    hB[0] = (bf16_t*)alloc(HBSZ); hB[1] = (bf16_t*)alloc(HBSZ); hB[2] = (bf16_t*)alloc(HBSZ);
    const size_t zeroBytes = 3 * HFSZ + 3 * HBSZ;
    hF[3] = (float*)alloc(HFSZ); hF[4] = (float*)alloc(HFSZ); hF[5] = (float*)alloc(HFSZ);
    hB[3] = (bf16_t*)alloc(HBSZ); hB[4] = (bf16_t*)alloc(HBSZ); hB[5] = (bf16_t*)alloc(HBSZ);
    bf16_t* bu0 = (bf16_t*)alloc((size_t)TSEQ * PSZ * 2);
    bf16_t* bu  = (bf16_t*)alloc((size_t)3 * PSZ * 2);
    bf16_t* rh  = (bf16_t*)alloc((size_t)3 * RHSZ * 2);
    float*  zb  = (float*) alloc((size_t)3 * ZSZ * 4);
    bf16_t* WpIn0 = (bf16_t*)alloc((size_t)18432 * 2);
    bf16_t* WpE10 = (bf16_t*)alloc((size_t)18432 * 2);
    bf16_t* WpE21 = (bf16_t*)alloc((size_t)18432 * 2);
    bf16_t* WpInt[3], *WpG[3], *WpC[3];
    for (int n = 0; n < 3; ++n) WpInt[n] = (bf16_t*)alloc((size_t)9216 * 2);
    for (int n = 0; n < 3; ++n) WpG[n]   = (bf16_t*)alloc((size_t)110592 * 2);
    for (int n = 0; n < 3; ++n) WpC[n]   = (bf16_t*)alloc((size_t)55296 * 2);

    hipMemsetAsync(hF[0], 0, zeroBytes, stream);

    // ---- weight packing (one dispatch) ----
    PackArgs PA{};
    int beg = 0;
    auto seg = [&](int i, const float* src, bf16_t* dst, int Cout, int CinPad, int CinReal) {
        PA.s[i] = {src, dst, Cout / 16, CinPad / 32, CinReal, beg};
        beg += 9 * (CinPad / 32) * (Cout / 16) * 512;
    };
    seg(0, Win0, WpIn0, 32, 64, 3);
    seg(1, We10, WpE10, 32, 64, 64);
    seg(2, We21, WpE21, 32, 64, 64);
    for (int n = 0; n < 3; ++n) seg(3 + n, Wint[n], WpInt[n], 32, 32, 32);
    for (int n = 0; n < 3; ++n) seg(6 + n, Wg[n],   WpG[n],   128, 96, 96);
    for (int n = 0; n < 3; ++n) seg(9 + n, Wc[n],   WpC[n],   64, 96, 96);
    PA.total = beg;
    wpack_all<<<(PA.total + 255) / 256, 256, 0, stream>>>(PA);

    const int GXP = 256;   // projint: ROWS=2
    const int GXC = 512;   // gates/cand: ROWS=1
    const dim3 TP(512), TC(512);

    // ---- node0 bu for ALL 8 timesteps in one dispatch (x read + cast fused) ----
    {
        PJs PJ{};
        for (int t = 0; t < TSEQ; ++t) {
            PJ.u[t].Xf = x; PJ.u[t].t = t;
            PJ.u[t].Wpj = WpIn0; PJ.u[t].bpj = bin0;
            PJ.u[t].Wit = WpInt[0]; PJ.u[t].bit = bint[0];
            PJ.u[t].outB = bu0 + (long)t * PSZ;
        }
        projint_k<1><<<dim3(GXP, TSEQ), TP, 0, stream>>>(PJ);
    }

    // ---- recurrence: projint -> gates -> cand per step ----
    float*  hFc[3] = {hF[0], hF[1], hF[2]};
    float*  hFn[3] = {hF[3], hF[4], hF[5]};
    bf16_t* hBc[3] = {hB[0], hB[1], hB[2]};
    bf16_t* hBn[3] = {hB[3], hB[4], hB[5]};
    const bf16_t* WpE[2] = {WpE10, WpE21};
    const float*  beE[2] = {be10, be21};

    for (int t = 0; t < PT; ++t) {
        const int nLo = (t > 7) ? (t - 7) : 0;
        const int nHi = (t < 2) ? t : 2;
        const int nAct = nHi - nLo + 1;

        // projint for nodes {1,2} active this step
        if (t >= 1) {
            const int lo = (nLo > 1) ? nLo : 1;
            const int cnt = nHi - lo + 1;
            if (cnt > 0) {
                PJs PJ{};
                for (int i = 0; i < cnt; ++i) {
                    int n = lo + i;
                    PJ.u[i].X = hBc[n - 1];
                    PJ.u[i].Wpj = WpE[n - 1]; PJ.u[i].bpj = beE[n - 1];
                    PJ.u[i].Wit = WpInt[n];   PJ.u[i].bit = bint[n];
                    PJ.u[i].outB = bu + (long)n * PSZ;
                }
                projint_k<0><<<dim3(GXP, cnt), TP, 0, stream>>>(PJ);
            }
        }
        // gates (512 thr, 8 waves)
        {
            NPs P{};
            for (int i = 0; i < nAct; ++i) {
                int n = nLo + i;
                P.n[i].A0 = (n == 0) ? (bu0 + (long)t * PSZ) : (bu + (long)n * PSZ);
                P.n[i].A1 = hBc[n]; P.n[i].Hb = hBc[n];
                P.n[i].Wp = WpG[n]; P.n[i].bias = bg[n];
                P.n[i].outB = rh + (long)n * RHSZ; P.n[i].outF = zb + (long)n * ZSZ;
            }
            mconv<32, 64, 128, 1, 8, 2><<<dim3(GXC, nAct), TC, 0, stream>>>(P);
        }
        // cand (+GRU update); final step writes NCHW output directly
        if (t < PT - 1) {
            NPs P{};
            for (int i = 0; i < nAct; ++i) {
                int n = nLo + i;
                P.n[i].A0 = (n == 0) ? (bu0 + (long)t * PSZ) : (bu + (long)n * PSZ);
                P.n[i].A1 = rh + (long)n * RHSZ;
                P.n[i].Zf = zb + (long)n * ZSZ; P.n[i].Hf = hFc[n];
                P.n[i].Wp = WpC[n]; P.n[i].bias = bc[n];
                P.n[i].outB = hBn[n]; P.n[i].outF = hFn[n];
            }
            mconv<32, 64, 64, 2, 8, 2><<<dim3(GXC, nAct), TC, 0, stream>>>(P);
        } else {
            NPs P{};
            P.n[0].A0 = bu + (long)2 * PSZ;
            P.n[0].A1 = rh + (long)2 * RHSZ;
            P.n[0].Zf = zb + (long)2 * ZSZ; P.n[0].Hf = hFc[2];
            P.n[0].Wp = WpC[2]; P.n[0].bias = bc[2];
            P.n[0].outF = (float*)d_out;
            mconv<32, 64, 64, 3, 8, 2><<<dim3(GXC, 1), TC, 0, stream>>>(P);
        }
        for (int n = nLo; n <= nHi; ++n) {
            if (t == PT - 1) break;
            float* tf = hFc[n]; hFc[n] = hFn[n]; hFn[n] = tf;
            bf16_t* tb = hBc[n]; hBc[n] = hBn[n]; hBn[n] = tb;
        }
    }
}